// Round 9
// baseline (98.157 us; speedup 1.0000x reference)
//
#include <hip/hip_runtime.h>
#include <hip/hip_bf16.h>
#include <stdint.h>

// Problem constants (from reference)
#define BATCH 4096
#define D_X   1024
#define D_Y   512

constexpr float SIGMA_INV = 0.1f;    // 1/10.0
constexpr float EPS_THR   = 46.0f;

// ---- fast path: 64x64 triangular tiles, 1 wave per tile ----
constexpr int BMT   = 64;
constexpr int NT2   = BATCH / BMT;           // 64 tile-rows
constexpr int NBLK2 = NT2 * (NT2 + 1) / 2;   // 2080 (2080 % 8 == 0)
constexpr int XCH   = D_X / 8;               // 128 16B chunks per x row
constexpr int YCH   = D_Y / 8;               // 64 chunks per y row

// ---- fallback tiling (128^2, round-2 structure) ----
constexpr int BM = 128;
constexpr int NT = BATCH / BM;
constexpr int NBLK = NT * (NT + 1) / 2;

typedef __bf16 bf16x8 __attribute__((ext_vector_type(8)));
typedef float  f32x4  __attribute__((ext_vector_type(4)));
typedef unsigned short u16x8 __attribute__((ext_vector_type(8)));

__device__ __forceinline__ unsigned short f32_to_bf16_bits(float f) {
    unsigned int u = __builtin_bit_cast(unsigned int, f);
    unsigned int r = (u + 0x7FFFu + ((u >> 16) & 1u)) >> 16;  // RNE
    return (unsigned short)r;
}

// ===========================================================================
// FAST PATH kernel 1: f32 -> bf16 in FRAGMENT-TILED layout + bf16 row norms.
// Layout: xt[(R*XCH + c)*64 + r] = 16B chunk c (8 bf16 along k) of row R*64+r.
// A wave's MFMA fragment load (4 kgrp x 16 rows) = 4 contiguous 256B segments
// -> direct global->VGPR loads are fully coalesced; no LDS in the GEMM loop.
// Norms are computed FROM THE bf16 VALUES so d2 = ||x~i - x~j||^2 >= 0 exactly.
// Grid: 64 row-tiles x 6 segments (4 x-chunkgroups + 2 y-chunkgroups).
// ===========================================================================
__global__ void __launch_bounds__(256)
convert_kernel(const float* __restrict__ x, const float* __restrict__ y,
               u16x8* __restrict__ xt, u16x8* __restrict__ yt,
               float* __restrict__ sqx, float* __restrict__ sqy) {
    __shared__ u16x8 L[64 * 32];          // 32 KB transpose staging
    __shared__ float pn[4][64];
    const int R   = blockIdx.x / 6;
    const int seg = blockIdx.x % 6;
    const int t = threadIdx.x, w = t >> 6, l = t & 63;
    const bool isx = (seg < 4);
    const int  cg  = isx ? seg : seg - 4;
    const float* src = isx ? x : y;
    const int  ld  = isx ? D_X : D_Y;

    // fill: coalesced row-major reads, convert, LDS (XOR c-swizzle per row)
#pragma unroll
    for (int it = 0; it < 8; ++it) {
        int idx = it * 256 + t;
        int r = idx >> 5, c = idx & 31;
        const float4* p = (const float4*)(src + (size_t)(R * 64 + r) * ld + (cg * 32 + c) * 8);
        float4 f0 = p[0], f1 = p[1];
        u16x8 v;
        v[0] = f32_to_bf16_bits(f0.x); v[1] = f32_to_bf16_bits(f0.y);
        v[2] = f32_to_bf16_bits(f0.z); v[3] = f32_to_bf16_bits(f0.w);
        v[4] = f32_to_bf16_bits(f1.x); v[5] = f32_to_bf16_bits(f1.y);
        v[6] = f32_to_bf16_bits(f1.z); v[7] = f32_to_bf16_bits(f1.w);
        L[r * 32 + (c ^ (r & 31))] = v;
    }
    __syncthreads();
    // drain: transposed read, coalesced tiled-layout write, norm partials
    float nrm = 0.f;
#pragma unroll
    for (int it = 0; it < 8; ++it) {
        int idx = it * 256 + t;
        int c = idx >> 6, r = idx & 63;        // c = it*4 + w, r = l
        u16x8 v = L[r * 32 + (c ^ (r & 31))];
        if (isx) xt[((size_t)R * XCH + cg * 32 + c) * 64 + r] = v;
        else     yt[((size_t)R * YCH + cg * 32 + c) * 64 + r] = v;
#pragma unroll
        for (int e = 0; e < 8; ++e) {
            float f = __builtin_bit_cast(float, (uint32_t)v[e] << 16);
            nrm = fmaf(f, f, nrm);
        }
    }
    pn[w][l] = nrm;
    __syncthreads();
    if (t < 64) {
        float s = pn[0][t] + pn[1][t] + pn[2][t] + pn[3][t];
        atomicAdd((isx ? sqx : sqy) + R * 64 + t, s);
    }
}

// ===========================================================================
// FAST PATH kernel 2: 1-wave 64^2 tiles, register-direct fragments, no LDS
// hot loop, no barriers. 4x4 fragments (0.5 loads/MFMA). Software pipeline
// with two named frag buffers; compiler inserts counted vmcnt waits.
// ===========================================================================
__device__ __forceinline__ void loadf(int s, int bi, int bj,
                                      const u16x8* __restrict__ xt,
                                      const u16x8* __restrict__ yt,
                                      int lrow, int kgrp,
                                      bf16x8 A[4], bf16x8 B[4]) {
    const u16x8 *pa, *pb;
    if (s < 32) {                                  // X steps: K chunks s*4..s*4+3
        pa = xt + ((size_t)bi * XCH + s * 4 + kgrp) * 64 + lrow;
        pb = xt + ((size_t)bj * XCH + s * 4 + kgrp) * 64 + lrow;
    } else {                                       // Y steps
        int sy = s - 32;
        pa = yt + ((size_t)bi * YCH + sy * 4 + kgrp) * 64 + lrow;
        pb = yt + ((size_t)bj * YCH + sy * 4 + kgrp) * 64 + lrow;
    }
#pragma unroll
    for (int m = 0; m < 4; ++m) {                  // imm offsets m*256B
        A[m] = __builtin_bit_cast(bf16x8, pa[m * 16]);
        B[m] = __builtin_bit_cast(bf16x8, pb[m * 16]);
    }
}

__device__ __forceinline__ void mfma16(const bf16x8 A[4], const bf16x8 B[4],
                                       f32x4 acc[4][4]) {
    __builtin_amdgcn_s_setprio(1);
#pragma unroll
    for (int m = 0; m < 4; ++m)
#pragma unroll
        for (int n = 0; n < 4; ++n)
            acc[m][n] = __builtin_amdgcn_mfma_f32_16x16x32_bf16(
                A[m], B[n], acc[m][n], 0, 0, 0);
    __builtin_amdgcn_s_setprio(0);
}

__global__ void __launch_bounds__(64)
gram_kernel(const u16x8* __restrict__ xt, const u16x8* __restrict__ yt,
            const float* __restrict__ sqx, const float* __restrict__ sqy,
            float* __restrict__ out) {
    __shared__ float snxA[64], snxB[64], snyA[64], snyB[64];   // 1 KB
    const int lane = threadIdx.x;
    const int lrow = lane & 15;
    const int kgrp = lane >> 4;

    // chunked XCD swizzle (bijective: 2080 % 8 == 0)
    int sb = (blockIdx.x & 7) * (NBLK2 / 8) + (blockIdx.x >> 3);

    // supertile-blocked triangular order: 8x8-tile squares (16 panels = 3 MB
    // < 4 MB per-XCD L2). Row I of supertiles: 1 diag (36 tiles) + (7-I)
    // off-diag (64 tiles each).
    int I = 0;
    for (;;) {
        int rowlen = 36 + (7 - I) * 64;
        if (sb < rowlen) break;
        sb -= rowlen; ++I;
    }
    int bi, bj;
    if (sb < 36) {                      // diagonal supertile: triangular inner
        int ti = 0;
        while (sb >= 8 - ti) { sb -= 8 - ti; ++ti; }
        bi = I * 8 + ti;
        bj = I * 8 + ti + sb;
    } else {
        int s2 = sb - 36;
        int J  = I + 1 + (s2 >> 6);
        int r  = s2 & 63;
        bi = I * 8 + (r >> 3);
        bj = J * 8 + (r & 7);
    }
    const bool diag = (bi == bj);

    // stage norms to LDS (1 wave; barrier just guarantees LDS ordering)
    snxA[lane] = sqx[bi * 64 + lane];
    snxB[lane] = sqx[bj * 64 + lane];
    snyA[lane] = sqy[bi * 64 + lane];
    snyB[lane] = sqy[bj * 64 + lane];
    __syncthreads();

    f32x4 accX[4][4] = {};
    f32x4 accY[4][4] = {};
    bf16x8 a0[4], b0[4], a1[4], b1[4];

    // prologue: 2 steps in flight (16 loads); first mfma waits vmcnt(8)
    loadf(0, bi, bj, xt, yt, lrow, kgrp, a0, b0);
    loadf(1, bi, bj, xt, yt, lrow, kgrp, a1, b1);

    // X phase: steps 0..31 (prefetch reaches steps 32,33 = Y, handled by s<32)
    for (int g = 0; g < 16; ++g) {
        mfma16(a0, b0, accX);
        loadf(2 * g + 2, bi, bj, xt, yt, lrow, kgrp, a0, b0);
        mfma16(a1, b1, accX);
        loadf(2 * g + 3, bi, bj, xt, yt, lrow, kgrp, a1, b1);
    }
    // Y phase: steps 32..45 with prefetch to 47
    for (int g = 0; g < 7; ++g) {
        mfma16(a0, b0, accY);
        loadf(34 + 2 * g, bi, bj, xt, yt, lrow, kgrp, a0, b0);
        mfma16(a1, b1, accY);
        loadf(35 + 2 * g, bi, bj, xt, yt, lrow, kgrp, a1, b1);
    }
    mfma16(a0, b0, accY);   // step 46
    mfma16(a1, b1, accY);   // step 47

    // Epilogue: C/D layout col=lane&15, row=(lane>>4)*4+reg (m89)
    float local = 0.f;
#pragma unroll
    for (int m = 0; m < 4; ++m) {
#pragma unroll
        for (int n = 0; n < 4; ++n) {
            int col   = n * 16 + lrow;
            float sxj = snxB[col];
            float syj = snyB[col];
#pragma unroll
            for (int r = 0; r < 4; ++r) {
                int rowi  = m * 16 + kgrp * 4 + r;
                float d2x = snxA[rowi] + sxj - 2.f * accX[m][n][r];
                float dxv = sqrtf(fmaxf(d2x, 1e-12f));
                float d2y = snyA[rowi] + syj - 2.f * accY[m][n][r];
                float dyv = sqrtf(fmaxf(d2y, 1e-12f));
                int gi = bi * 64 + rowi, gj = bj * 64 + col;
                bool keep = (gi != gj) && (dxv <= EPS_THR);
                float contrib = __expf(-dxv * SIGMA_INV) * dyv;
                local += keep ? contrib : 0.f;
            }
        }
    }
    if (!diag) local *= 2.f;

#pragma unroll
    for (int off = 32; off > 0; off >>= 1)
        local += __shfl_down(local, off, 64);
    if (lane == 0)
        atomicAdd(out, local);
}

// ===========================================================================
// FALLBACK PATH (used only if ws_size is too small) — round-2 structure.
// ===========================================================================
__global__ void norms_kernel_fb(const float* __restrict__ x,
                                const float* __restrict__ y,
                                float* __restrict__ sqx,
                                float* __restrict__ sqy) {
    int row = blockIdx.x;
    int t   = threadIdx.x;
    const float4* xr = (const float4*)(x + (size_t)row * D_X);
    float sx = 0.f;
#pragma unroll
    for (int i = 0; i < D_X / 4 / 64; ++i) {
        float4 v = xr[t + i * 64];
        sx += v.x * v.x + v.y * v.y + v.z * v.z + v.w * v.w;
    }
    const float4* yr = (const float4*)(y + (size_t)row * D_Y);
    float sy = 0.f;
#pragma unroll
    for (int i = 0; i < D_Y / 4 / 64; ++i) {
        float4 v = yr[t + i * 64];
        sy += v.x * v.x + v.y * v.y + v.z * v.z + v.w * v.w;
    }
#pragma unroll
    for (int off = 32; off > 0; off >>= 1) {
        sx += __shfl_down(sx, off, 64);
        sy += __shfl_down(sy, off, 64);
    }
    if (t == 0) { sqx[row] = sx; sqy[row] = sy; }
}

__device__ __forceinline__ void stage_tile_fb(const float* __restrict__ src, int ld,
                                              int base_row, int k0,
                                              u16x8* __restrict__ dst, int tid) {
#pragma unroll
    for (int it = 0; it < 2; ++it) {
        int u   = tid + it * 256;
        int row = u >> 2;
        int q   = u & 3;
        const float4* p = (const float4*)(src + (size_t)(base_row + row) * ld + k0 + q * 16);
        float4 f0 = p[0], f1 = p[1], f2 = p[2], f3 = p[3];
        u16x8 lo, hi;
        lo[0] = f32_to_bf16_bits(f0.x); lo[1] = f32_to_bf16_bits(f0.y);
        lo[2] = f32_to_bf16_bits(f0.z); lo[3] = f32_to_bf16_bits(f0.w);
        lo[4] = f32_to_bf16_bits(f1.x); lo[5] = f32_to_bf16_bits(f1.y);
        lo[6] = f32_to_bf16_bits(f1.z); lo[7] = f32_to_bf16_bits(f1.w);
        hi[0] = f32_to_bf16_bits(f2.x); hi[1] = f32_to_bf16_bits(f2.y);
        hi[2] = f32_to_bf16_bits(f2.z); hi[3] = f32_to_bf16_bits(f2.w);
        hi[4] = f32_to_bf16_bits(f3.x); hi[5] = f32_to_bf16_bits(f3.y);
        hi[6] = f32_to_bf16_bits(f3.z); hi[7] = f32_to_bf16_bits(f3.w);
        int swz = row & 7;
        dst[row * 8 + ((2 * q) ^ swz)]     = lo;
        dst[row * 8 + ((2 * q + 1) ^ swz)] = hi;
    }
}

__device__ __forceinline__ void mfma16_fb(const bf16x8 a[4], const bf16x8 b[4],
                                          f32x4 acc[4][4]) {
#pragma unroll
    for (int m = 0; m < 4; ++m)
#pragma unroll
        for (int n = 0; n < 4; ++n)
            acc[m][n] = __builtin_amdgcn_mfma_f32_16x16x32_bf16(
                a[m], b[n], acc[m][n], 0, 0, 0);
}

__device__ __forceinline__ void load_frags_fb(const u16x8* As_, const u16x8* Bs_,
                                              int wr, int wc, int lrow, int kgrp,
                                              bf16x8 a[2][4], bf16x8 b[2][4]) {
#pragma unroll
    for (int ks = 0; ks < 2; ++ks) {
#pragma unroll
        for (int m = 0; m < 4; ++m) {
            int row  = wr * 64 + m * 16 + lrow;
            int slot = (ks * 4 + kgrp) ^ (row & 7);
            a[ks][m] = __builtin_bit_cast(bf16x8, As_[row * 8 + slot]);
        }
#pragma unroll
        for (int n = 0; n < 4; ++n) {
            int row  = wc * 64 + n * 16 + lrow;
            int slot = (ks * 4 + kgrp) ^ (row & 7);
            b[ks][n] = __builtin_bit_cast(bf16x8, Bs_[row * 8 + slot]);
        }
    }
}

__global__ void __launch_bounds__(256, 2)
graph_loss_fb(const float* __restrict__ x, const float* __restrict__ y,
              const float* __restrict__ sqx, const float* __restrict__ sqy,
              float* __restrict__ out) {
    __shared__ u16x8 As[BM * 8];
    __shared__ u16x8 Bs[BM * 8];
    __shared__ float snxA[BM], snxB[BM], snyA[BM], snyB[BM];
    __shared__ float wsum[4];

    const int tid  = threadIdx.x;
    const int lane = tid & 63;
    const int wid  = tid >> 6;
    const int wr   = wid >> 1;
    const int wc   = wid & 1;
    const int lrow = lane & 15;
    const int kgrp = lane >> 4;

    int t = blockIdx.x, bi = 0;
    while (t >= NT - bi) { t -= NT - bi; ++bi; }
    const int bj = bi + t;
    const int iA = bi * BM;
    const int iB = bj * BM;

    if (tid < BM) {
        snxA[tid] = sqx[iA + tid];
        snyA[tid] = sqy[iA + tid];
        snxB[tid] = sqx[iB + tid];
        snyB[tid] = sqy[iB + tid];
    }

    f32x4 accX[4][4] = {};
    f32x4 accY[4][4] = {};
    bf16x8 a[2][4], b[2][4];

    for (int kt = 0; kt < D_X / 64; ++kt) {
        __syncthreads();
        stage_tile_fb(x, D_X, iA, kt * 64, As, tid);
        stage_tile_fb(x, D_X, iB, kt * 64, Bs, tid);
        __syncthreads();
        load_frags_fb(As, Bs, wr, wc, lrow, kgrp, a, b);
#pragma unroll
        for (int ks = 0; ks < 2; ++ks) mfma16_fb(a[ks], b[ks], accX);
    }
    for (int kt = 0; kt < D_Y / 64; ++kt) {
        __syncthreads();
        stage_tile_fb(y, D_Y, iA, kt * 64, As, tid);
        stage_tile_fb(y, D_Y, iB, kt * 64, Bs, tid);
        __syncthreads();
        load_frags_fb(As, Bs, wr, wc, lrow, kgrp, a, b);
#pragma unroll
        for (int ks = 0; ks < 2; ++ks) mfma16_fb(a[ks], b[ks], accY);
    }

    float local = 0.f;
#pragma unroll
    for (int m = 0; m < 4; ++m) {
#pragma unroll
        for (int n = 0; n < 4; ++n) {
            int col   = wc * 64 + n * 16 + lrow;
            float sxj = snxB[col];
            float syj = snyB[col];
#pragma unroll
            for (int r = 0; r < 4; ++r) {
                int rowi  = wr * 64 + m * 16 + kgrp * 4 + r;
                float d2x = snxA[rowi] + sxj - 2.f * accX[m][n][r];
                float dxv = sqrtf(fmaxf(d2x, 1e-12f));
                float d2y = snyA[rowi] + syj - 2.f * accY[m][n][r];
                float dyv = sqrtf(fmaxf(d2y, 1e-12f));
                int gi = iA + rowi, gj = iB + col;
                bool keep = (gi != gj) && (dxv <= EPS_THR);
                float contrib = __expf(-dxv * SIGMA_INV) * dyv;
                local += keep ? contrib : 0.f;
            }
        }
    }
    if (bi != bj) local *= 2.f;

#pragma unroll
    for (int off = 32; off > 0; off >>= 1)
        local += __shfl_down(local, off, 64);
    if (lane == 0) wsum[wid] = local;
    __syncthreads();
    if (tid == 0)
        atomicAdd(out, wsum[0] + wsum[1] + wsum[2] + wsum[3]);
}

// ===========================================================================
extern "C" void kernel_launch(void* const* d_in, const int* in_sizes, int n_in,
                              void* d_out, int out_size, void* d_ws, size_t ws_size,
                              hipStream_t stream) {
    const float* x = (const float*)d_in[0];
    const float* y = (const float*)d_in[1];
    float* out = (float*)d_out;

    hipMemsetAsync(d_out, 0, sizeof(float) * (size_t)out_size, stream);

    const size_t xt_bytes = (size_t)BATCH * XCH * 16;   // 8 MB
    const size_t yt_bytes = (size_t)BATCH * YCH * 16;   // 4 MB
    const size_t sq_bytes = 2 * (size_t)BATCH * sizeof(float);
    const size_t need = xt_bytes + yt_bytes + sq_bytes;

    if (ws_size >= need) {
        u16x8* xt  = (u16x8*)d_ws;
        u16x8* yt  = (u16x8*)((char*)d_ws + xt_bytes);
        float* sqx = (float*)((char*)d_ws + xt_bytes + yt_bytes);
        float* sqy = sqx + BATCH;
        // norms are atomically accumulated -> zero them each launch
        hipMemsetAsync(sqx, 0, sq_bytes, stream);
        convert_kernel<<<64 * 6, 256, 0, stream>>>(x, y, xt, yt, sqx, sqy);
        gram_kernel<<<NBLK2, 64, 0, stream>>>(xt, yt, sqx, sqy, out);
    } else {
        float* sqx = (float*)d_ws;
        float* sqy = sqx + BATCH;
        norms_kernel_fb<<<BATCH, 64, 0, stream>>>(x, y, sqx, sqy);
        graph_loss_fb<<<NBLK, 256, 0, stream>>>(x, y, sqx, sqy, out);
    }
}

// Round 10
// 63.736 us; speedup vs baseline: 1.5401x; 1.5401x over previous
//
#include <hip/hip_runtime.h>
#include <hip/hip_bf16.h>
#include <hip/hip_fp8.h>
#include <stdint.h>

// Problem constants (from reference)
#define BATCH 4096
#define D_X   1024
#define D_Y   512

constexpr float SIGMA_INV = 0.1f;    // 1/10.0
constexpr float EPS_THR   = 46.0f;

// ---- fast path: fp8 e4m3, 64x64 triangular tiles ----
constexpr int BM2   = 64;
constexpr int NT2   = BATCH / BM2;           // 64 tile-rows
constexpr int NBLK2 = NT2 * (NT2 + 1) / 2;   // 2080 (2080 % 8 == 0)
constexpr int XS8   = D_X / 16;              // 64 16B slots per fp8 x row
constexpr int YS8   = D_Y / 16;              // 32 slots per fp8 y row
constexpr int NSX8  = D_X / 128;             // 8 X K-steps (BK=128)
constexpr int NS8   = NSX8 + D_Y / 128;      // 12 total K-steps

// ---- fallback tiling (128^2 bf16, round-2 structure) ----
constexpr int BM = 128;
constexpr int NT = BATCH / BM;
constexpr int NBLK = NT * (NT + 1) / 2;

typedef __bf16 bf16x8 __attribute__((ext_vector_type(8)));
typedef float  f32x4  __attribute__((ext_vector_type(4)));
typedef unsigned short u16x8 __attribute__((ext_vector_type(8)));
typedef unsigned long long u64;

__device__ __forceinline__ unsigned short f32_to_bf16_bits(float f) {
    unsigned int u = __builtin_bit_cast(unsigned int, f);
    unsigned int r = (u + 0x7FFFu + ((u >> 16) & 1u)) >> 16;  // RNE
    return (unsigned short)r;
}

// ===========================================================================
// FAST PATH kernel 1: f32 -> fp8 e4m3 (linear k-order) + norms of the
// QUANTIZED values (so d2 = ||q_i - q_j||^2 is exact for quantized vectors).
// One block per row: t<128 -> 8 x elems each (8B store), t in [128,192) -> y.
// ===========================================================================
__global__ void __launch_bounds__(192)
convert_fp8(const float* __restrict__ x, const float* __restrict__ y,
            u64* __restrict__ xq, u64* __restrict__ yq,
            float* __restrict__ sqx, float* __restrict__ sqy) {
    __shared__ float part[2];
    const int row = blockIdx.x;
    const int t   = threadIdx.x;
    const int lane = t & 63;
    const int wid  = t >> 6;

    float nrm = 0.f;
    if (t < 128) {
        const float4* p = (const float4*)(x + (size_t)row * D_X + t * 8);
        float4 f0 = p[0], f1 = p[1];
        float e[8] = {f0.x, f0.y, f0.z, f0.w, f1.x, f1.y, f1.z, f1.w};
        u64 w = 0;
#pragma unroll
        for (int i = 0; i < 8; ++i) {
            __hip_fp8_e4m3 q(e[i]);                  // RNE + saturate (OCP)
            float b = (float)q;
            nrm = fmaf(b, b, nrm);
            w |= (u64)q.__x << (8 * i);
        }
        xq[(size_t)row * 128 + t] = w;               // 128 u64 per x row
    } else {
        int o = t - 128;                             // 0..63
        const float4* p = (const float4*)(y + (size_t)row * D_Y + o * 8);
        float4 f0 = p[0], f1 = p[1];
        float e[8] = {f0.x, f0.y, f0.z, f0.w, f1.x, f1.y, f1.z, f1.w};
        u64 w = 0;
#pragma unroll
        for (int i = 0; i < 8; ++i) {
            __hip_fp8_e4m3 q(e[i]);
            float b = (float)q;
            nrm = fmaf(b, b, nrm);
            w |= (u64)q.__x << (8 * i);
        }
        yq[(size_t)row * 64 + o] = w;                // 64 u64 per y row
    }
#pragma unroll
    for (int off = 32; off > 0; off >>= 1)
        nrm += __shfl_down(nrm, off, 64);
    if (lane == 0) {
        if (wid < 2) part[wid] = nrm;
        else         sqy[row] = nrm;
    }
    __syncthreads();
    if (t == 0) sqx[row] = part[0] + part[1];
}

// ===========================================================================
// FAST PATH kernel 2: fused fp8 Gram(x), Gram(y) -> masked loss.
// R8 sync skeleton (validated): 64^2 tiles, combined A|B LDS tile
// [128 rows][8 x 16B slots] (16 KB), BK=128 fp8 -> 12 steps, 2 buffers,
// depth-2 counted vmcnt(4), 4 blocks/CU.
// ===========================================================================

// Issue one step's staging. LDS dest LINEAR; XOR slot swizzle computed in the
// per-lane GLOBAL source address (rule #21). 4 gload_lds/thread = 4 vmcnt.
__device__ __forceinline__ void issue8(int s,
                                       const u16x8* __restrict__ xq,
                                       const u16x8* __restrict__ yq,
                                       int iA, int iB,
                                       u16x8* dst, int tid) {
    const int wid = tid >> 6, lane = tid & 63;
    const u16x8* src; int rs, k0;
    if (s < NSX8) { src = xq; rs = XS8; k0 = s * 8; }
    else          { src = yq; rs = YS8; k0 = (s - NSX8) * 8; }
#pragma unroll
    for (int it = 0; it < 4; ++it) {
        int u   = it * 256 + wid * 64;   // wave-uniform LDS slot base
        int ul  = u + lane;
        int row = ul >> 3;               // 0..127
        int st  = ul & 7;
        int lg  = st ^ (row & 7);
        int grow = (row < 64 ? iA + row : iB + row - 64);
        const u16x8* g = src + (size_t)grow * rs + k0 + lg;
        __builtin_amdgcn_global_load_lds(
            (const uint32_t __attribute__((address_space(1)))*)g,
            (uint32_t __attribute__((address_space(3)))*)(dst + u), 16, 0, 0);
    }
}

// fp8 fragment read: 8 bytes at k-unit u8 = ks*4+kgrp of row; slot-swizzled.
__device__ __forceinline__ u64 ldsfrag(const u16x8* T, int row, int u8) {
    int slot = (u8 >> 1) ^ (row & 7);
    const char* p = (const char*)T + row * 128 + slot * 16 + (u8 & 1) * 8;
    return *(const u64*)p;
}

// One pipeline step (depth-2 counted; W never 0 until the last step).
#define GSTEP8(BUF, T, ACC, W)                                             \
    {                                                                      \
        asm volatile("s_waitcnt vmcnt(" #W ")" ::: "memory");              \
        __builtin_amdgcn_s_barrier();                                      \
        u64 fa[4][2], fb[4][2];                                            \
        _Pragma("unroll")                                                  \
        for (int ks = 0; ks < 4; ++ks) {                                   \
            _Pragma("unroll")                                              \
            for (int m = 0; m < 2; ++m)                                    \
                fa[ks][m] = ldsfrag(BUF, wr * 32 + m * 16 + lrow,          \
                                    ks * 4 + kgrp);                        \
            _Pragma("unroll")                                              \
            for (int n = 0; n < 2; ++n)                                    \
                fb[ks][n] = ldsfrag(BUF, 64 + wc * 32 + n * 16 + lrow,     \
                                    ks * 4 + kgrp);                        \
        }                                                                  \
        asm volatile("s_waitcnt lgkmcnt(0)" ::: "memory");                 \
        __builtin_amdgcn_s_barrier();                                      \
        issue8((T) + 2, xq, yq, iA, iB, BUF, tid);                         \
        __builtin_amdgcn_s_setprio(1);                                     \
        _Pragma("unroll")                                                  \
        for (int ks = 0; ks < 4; ++ks)                                     \
            _Pragma("unroll")                                              \
            for (int m = 0; m < 2; ++m)                                    \
                _Pragma("unroll")                                          \
                for (int n = 0; n < 2; ++n)                                \
                    ACC[m][n] = __builtin_amdgcn_mfma_f32_16x16x32_fp8_fp8(\
                        (long)fa[ks][m], (long)fb[ks][n], ACC[m][n],       \
                        0, 0, 0);                                          \
        __builtin_amdgcn_s_setprio(0);                                     \
    }
#define GSTEP8_NOISSUE(BUF, ACC, W)                                        \
    {                                                                      \
        asm volatile("s_waitcnt vmcnt(" #W ")" ::: "memory");              \
        __builtin_amdgcn_s_barrier();                                      \
        u64 fa[4][2], fb[4][2];                                            \
        _Pragma("unroll")                                                  \
        for (int ks = 0; ks < 4; ++ks) {                                   \
            _Pragma("unroll")                                              \
            for (int m = 0; m < 2; ++m)                                    \
                fa[ks][m] = ldsfrag(BUF, wr * 32 + m * 16 + lrow,          \
                                    ks * 4 + kgrp);                        \
            _Pragma("unroll")                                              \
            for (int n = 0; n < 2; ++n)                                    \
                fb[ks][n] = ldsfrag(BUF, 64 + wc * 32 + n * 16 + lrow,     \
                                    ks * 4 + kgrp);                        \
        }                                                                  \
        __builtin_amdgcn_s_setprio(1);                                     \
        _Pragma("unroll")                                                  \
        for (int ks = 0; ks < 4; ++ks)                                     \
            _Pragma("unroll")                                              \
            for (int m = 0; m < 2; ++m)                                    \
                _Pragma("unroll")                                          \
                for (int n = 0; n < 2; ++n)                                \
                    ACC[m][n] = __builtin_amdgcn_mfma_f32_16x16x32_fp8_fp8(\
                        (long)fa[ks][m], (long)fb[ks][n], ACC[m][n],       \
                        0, 0, 0);                                          \
        __builtin_amdgcn_s_setprio(0);                                     \
    }

__global__ void __launch_bounds__(256, 4)
gram_fp8(const u16x8* __restrict__ xq, const u16x8* __restrict__ yq,
         const float* __restrict__ sqx, const float* __restrict__ sqy,
         float* __restrict__ out) {
    __shared__ u16x8 T0[1024], T1[1024];   // 2 x 16 KB combined A|B tiles
    __shared__ float snxA[BM2], snxB[BM2], snyA[BM2], snyB[BM2];
    __shared__ float wsum[4];

    const int tid  = threadIdx.x;
    const int lane = tid & 63;
    const int wid  = tid >> 6;
    const int wr   = wid >> 1;
    const int wc   = wid & 1;
    const int lrow = lane & 15;
    const int kgrp = lane >> 4;

    // T1: chunked XCD swizzle (bijective: NBLK2 % 8 == 0).
    int sb = (blockIdx.x & 7) * (NBLK2 / 8) + (blockIdx.x >> 3);

    // triangular tile mapping
    int t0 = sb, bi = 0;
    while (t0 >= NT2 - bi) { t0 -= NT2 - bi; ++bi; }
    const int bj = bi + t0;
    const int iA = bi * BM2;
    const int iB = bj * BM2;
    const bool diag = (bi == bj);

    if (tid < BM2) {
        snxA[tid] = sqx[iA + tid];
        snyA[tid] = sqy[iA + tid];
        snxB[tid] = sqx[iB + tid];
        snyB[tid] = sqy[iB + tid];
    }

    f32x4 accX[2][2] = {};
    f32x4 accY[2][2] = {};

    // prologue: pre-issue steps 0,1 (8 loads in flight; no drain)
    issue8(0, xq, yq, iA, iB, T0, tid);
    issue8(1, xq, yq, iA, iB, T1, tid);

    // X phase: steps 0..7 (BK=128)
    for (int g = 0; g < 4; ++g) {
        GSTEP8(T0, 2 * g,     accX, 4);   // issues 2g+2
        GSTEP8(T1, 2 * g + 1, accX, 4);   // issues 2g+3 (g=3 -> 9, Y ok)
    }
    // Y phase: steps 8,9 with issues 10,11
    GSTEP8(T0, 8, accY, 4);
    GSTEP8(T1, 9, accY, 4);
    // peeled tail: steps 10,11
    GSTEP8_NOISSUE(T0, accY, 4);          // step 10 (batch 11 in flight)
    GSTEP8_NOISSUE(T1, accY, 0);          // step 11 (full drain)

    // Epilogue: C/D layout col=lane&15, row=(lane>>4)*4+reg (m89, dtype-indep)
    float local = 0.f;
#pragma unroll
    for (int m = 0; m < 2; ++m) {
#pragma unroll
        for (int n = 0; n < 2; ++n) {
            int col   = wc * 32 + n * 16 + lrow;
            float sxj = snxB[col];
            float syj = snyB[col];
#pragma unroll
            for (int r = 0; r < 4; ++r) {
                int rowi  = wr * 32 + m * 16 + kgrp * 4 + r;
                float d2x = snxA[rowi] + sxj - 2.f * accX[m][n][r];
                float dxv = sqrtf(fmaxf(d2x, 1e-12f));
                float d2y = snyA[rowi] + syj - 2.f * accY[m][n][r];
                float dyv = sqrtf(fmaxf(d2y, 1e-12f));
                int gi = iA + rowi, gj = iB + col;
                bool keep = (gi != gj) && (dxv <= EPS_THR);
                float contrib = __expf(-dxv * SIGMA_INV) * dyv;
                local += keep ? contrib : 0.f;
            }
        }
    }
    if (!diag) local *= 2.f;

#pragma unroll
    for (int off = 32; off > 0; off >>= 1)
        local += __shfl_down(local, off, 64);
    if (lane == 0) wsum[wid] = local;
    __syncthreads();
    if (tid == 0)
        atomicAdd(out, wsum[0] + wsum[1] + wsum[2] + wsum[3]);
}

// ===========================================================================
// FALLBACK PATH (bf16, round-2 structure) — used only if ws too small.
// ===========================================================================
__global__ void norms_kernel_fb(const float* __restrict__ x,
                                const float* __restrict__ y,
                                float* __restrict__ sqx,
                                float* __restrict__ sqy) {
    int row = blockIdx.x;
    int t   = threadIdx.x;
    const float4* xr = (const float4*)(x + (size_t)row * D_X);
    float sx = 0.f;
#pragma unroll
    for (int i = 0; i < D_X / 4 / 64; ++i) {
        float4 v = xr[t + i * 64];
        sx += v.x * v.x + v.y * v.y + v.z * v.z + v.w * v.w;
    }
    const float4* yr = (const float4*)(y + (size_t)row * D_Y);
    float sy = 0.f;
#pragma unroll
    for (int i = 0; i < D_Y / 4 / 64; ++i) {
        float4 v = yr[t + i * 64];
        sy += v.x * v.x + v.y * v.y + v.z * v.z + v.w * v.w;
    }
#pragma unroll
    for (int off = 32; off > 0; off >>= 1) {
        sx += __shfl_down(sx, off, 64);
        sy += __shfl_down(sy, off, 64);
    }
    if (t == 0) { sqx[row] = sx; sqy[row] = sy; }
}

__device__ __forceinline__ void stage_tile_fb(const float* __restrict__ src, int ld,
                                              int base_row, int k0,
                                              u16x8* __restrict__ dst, int tid) {
#pragma unroll
    for (int it = 0; it < 2; ++it) {
        int u   = tid + it * 256;
        int row = u >> 2;
        int q   = u & 3;
        const float4* p = (const float4*)(src + (size_t)(base_row + row) * ld + k0 + q * 16);
        float4 f0 = p[0], f1 = p[1], f2 = p[2], f3 = p[3];
        u16x8 lo, hi;
        lo[0] = f32_to_bf16_bits(f0.x); lo[1] = f32_to_bf16_bits(f0.y);
        lo[2] = f32_to_bf16_bits(f0.z); lo[3] = f32_to_bf16_bits(f0.w);
        lo[4] = f32_to_bf16_bits(f1.x); lo[5] = f32_to_bf16_bits(f1.y);
        lo[6] = f32_to_bf16_bits(f1.z); lo[7] = f32_to_bf16_bits(f1.w);
        hi[0] = f32_to_bf16_bits(f2.x); hi[1] = f32_to_bf16_bits(f2.y);
        hi[2] = f32_to_bf16_bits(f2.z); hi[3] = f32_to_bf16_bits(f2.w);
        hi[4] = f32_to_bf16_bits(f3.x); hi[5] = f32_to_bf16_bits(f3.y);
        hi[6] = f32_to_bf16_bits(f3.z); hi[7] = f32_to_bf16_bits(f3.w);
        int swz = row & 7;
        dst[row * 8 + ((2 * q) ^ swz)]     = lo;
        dst[row * 8 + ((2 * q + 1) ^ swz)] = hi;
    }
}

__device__ __forceinline__ void mfma16_fb(const bf16x8 a[4], const bf16x8 b[4],
                                          f32x4 acc[4][4]) {
#pragma unroll
    for (int m = 0; m < 4; ++m)
#pragma unroll
        for (int n = 0; n < 4; ++n)
            acc[m][n] = __builtin_amdgcn_mfma_f32_16x16x32_bf16(
                a[m], b[n], acc[m][n], 0, 0, 0);
}

__device__ __forceinline__ void load_frags_fb(const u16x8* As_, const u16x8* Bs_,
                                              int wr, int wc, int lrow, int kgrp,
                                              bf16x8 a[2][4], bf16x8 b[2][4]) {
#pragma unroll
    for (int ks = 0; ks < 2; ++ks) {
#pragma unroll
        for (int m = 0; m < 4; ++m) {
            int row  = wr * 64 + m * 16 + lrow;
            int slot = (ks * 4 + kgrp) ^ (row & 7);
            a[ks][m] = __builtin_bit_cast(bf16x8, As_[row * 8 + slot]);
        }
#pragma unroll
        for (int n = 0; n < 4; ++n) {
            int row  = wc * 64 + n * 16 + lrow;
            int slot = (ks * 4 + kgrp) ^ (row & 7);
            b[ks][n] = __builtin_bit_cast(bf16x8, Bs_[row * 8 + slot]);
        }
    }
}

__global__ void __launch_bounds__(256, 2)
graph_loss_fb(const float* __restrict__ x, const float* __restrict__ y,
              const float* __restrict__ sqx, const float* __restrict__ sqy,
              float* __restrict__ out) {
    __shared__ u16x8 As[BM * 8];
    __shared__ u16x8 Bs[BM * 8];
    __shared__ float snxA[BM], snxB[BM], snyA[BM], snyB[BM];
    __shared__ float wsum[4];

    const int tid  = threadIdx.x;
    const int lane = tid & 63;
    const int wid  = tid >> 6;
    const int wr   = wid >> 1;
    const int wc   = wid & 1;
    const int lrow = lane & 15;
    const int kgrp = lane >> 4;

    int t = blockIdx.x, bi = 0;
    while (t >= NT - bi) { t -= NT - bi; ++bi; }
    const int bj = bi + t;
    const int iA = bi * BM;
    const int iB = bj * BM;

    if (tid < BM) {
        snxA[tid] = sqx[iA + tid];
        snyA[tid] = sqy[iA + tid];
        snxB[tid] = sqx[iB + tid];
        snyB[tid] = sqy[iB + tid];
    }

    f32x4 accX[4][4] = {};
    f32x4 accY[4][4] = {};
    bf16x8 a[2][4], b[2][4];

    for (int kt = 0; kt < D_X / 64; ++kt) {
        __syncthreads();
        stage_tile_fb(x, D_X, iA, kt * 64, As, tid);
        stage_tile_fb(x, D_X, iB, kt * 64, Bs, tid);
        __syncthreads();
        load_frags_fb(As, Bs, wr, wc, lrow, kgrp, a, b);
#pragma unroll
        for (int ks = 0; ks < 2; ++ks) mfma16_fb(a[ks], b[ks], accX);
    }
    for (int kt = 0; kt < D_Y / 64; ++kt) {
        __syncthreads();
        stage_tile_fb(y, D_Y, iA, kt * 64, As, tid);
        stage_tile_fb(y, D_Y, iB, kt * 64, Bs, tid);
        __syncthreads();
        load_frags_fb(As, Bs, wr, wc, lrow, kgrp, a, b);
#pragma unroll
        for (int ks = 0; ks < 2; ++ks) mfma16_fb(a[ks], b[ks], accY);
    }

    float local = 0.f;
#pragma unroll
    for (int m = 0; m < 4; ++m) {
#pragma unroll
        for (int n = 0; n < 4; ++n) {
            int col   = wc * 64 + n * 16 + lrow;
            float sxj = snxB[col];
            float syj = snyB[col];
#pragma unroll
            for (int r = 0; r < 4; ++r) {
                int rowi  = wr * 64 + m * 16 + kgrp * 4 + r;
                float d2x = snxA[rowi] + sxj - 2.f * accX[m][n][r];
                float dxv = sqrtf(fmaxf(d2x, 1e-12f));
                float d2y = snyA[rowi] + syj - 2.f * accY[m][n][r];
                float dyv = sqrtf(fmaxf(d2y, 1e-12f));
                int gi = iA + rowi, gj = iB + col;
                bool keep = (gi != gj) && (dxv <= EPS_THR);
                float contrib = __expf(-dxv * SIGMA_INV) * dyv;
                local += keep ? contrib : 0.f;
            }
        }
    }
    if (bi != bj) local *= 2.f;

#pragma unroll
    for (int off = 32; off > 0; off >>= 1)
        local += __shfl_down(local, off, 64);
    if (lane == 0) wsum[wid] = local;
    __syncthreads();
    if (tid == 0)
        atomicAdd(out, wsum[0] + wsum[1] + wsum[2] + wsum[3]);
}

// ===========================================================================
extern "C" void kernel_launch(void* const* d_in, const int* in_sizes, int n_in,
                              void* d_out, int out_size, void* d_ws, size_t ws_size,
                              hipStream_t stream) {
    const float* x = (const float*)d_in[0];
    const float* y = (const float*)d_in[1];
    float* out = (float*)d_out;

    hipMemsetAsync(d_out, 0, sizeof(float) * (size_t)out_size, stream);

    const size_t xq_bytes = (size_t)BATCH * D_X;        // 4 MB fp8
    const size_t yq_bytes = (size_t)BATCH * D_Y;        // 2 MB fp8
    const size_t sq_bytes = 2 * (size_t)BATCH * sizeof(float);
    const size_t need = xq_bytes + yq_bytes + sq_bytes;

    if (ws_size >= need) {
        u64*   xq  = (u64*)d_ws;
        u64*   yq  = (u64*)((char*)d_ws + xq_bytes);
        float* sqx = (float*)((char*)d_ws + xq_bytes + yq_bytes);
        float* sqy = sqx + BATCH;
        convert_fp8<<<BATCH, 192, 0, stream>>>(x, y, xq, yq, sqx, sqy);
        gram_fp8<<<NBLK2, 256, 0, stream>>>((const u16x8*)xq, (const u16x8*)yq,
                                            sqx, sqy, out);
    } else {
        float* sqx = (float*)d_ws;
        float* sqy = sqx + BATCH;
        norms_kernel_fb<<<BATCH, 64, 0, stream>>>(x, y, sqx, sqy);
        graph_loss_fb<<<NBLK, 256, 0, stream>>>(x, y, sqx, sqy, out);
    }
}

// Round 11
// 60.651 us; speedup vs baseline: 1.6184x; 1.0509x over previous
//
#include <hip/hip_runtime.h>
#include <hip/hip_bf16.h>
#include <hip/hip_fp8.h>
#include <stdint.h>

// Problem constants (from reference)
#define BATCH 4096
#define D_X   1024
#define D_Y   512

constexpr float SIGMA_INV = 0.1f;    // 1/10.0
constexpr float EPS_THR   = 46.0f;

// ---- fast path: fp8 e4m3, 64x64 triangular tiles ----
constexpr int BM2   = 64;
constexpr int NT2   = BATCH / BM2;           // 64 tile-rows
constexpr int NBLK2 = NT2 * (NT2 + 1) / 2;   // 2080 (2080 % 8 == 0)
constexpr int XS8   = D_X / 16;              // 64 16B slots per fp8 x row
constexpr int YS8   = D_Y / 16;              // 32 slots per fp8 y row
constexpr int NSX8  = D_X / 128;             // 8 X K-steps (BK=128)

// ---- fallback tiling (128^2 bf16, round-2 structure) ----
constexpr int BM = 128;
constexpr int NT = BATCH / BM;
constexpr int NBLK = NT * (NT + 1) / 2;

typedef __bf16 bf16x8 __attribute__((ext_vector_type(8)));
typedef float  f32x4  __attribute__((ext_vector_type(4)));
typedef unsigned short u16x8 __attribute__((ext_vector_type(8)));
typedef unsigned long long u64;
typedef u64 u64x2 __attribute__((ext_vector_type(2)));

__device__ __forceinline__ unsigned short f32_to_bf16_bits(float f) {
    unsigned int u = __builtin_bit_cast(unsigned int, f);
    unsigned int r = (u + 0x7FFFu + ((u >> 16) & 1u)) >> 16;  // RNE
    return (unsigned short)r;
}

// k-unit permutation: logical u8 (ks = u8>>2, kgrp = u8&3) -> stored pos so
// that 16B chunk c = (ks>>1)*4 + kgrp holds the ks-pair {2t,2t+1} of kgrp.
// Makes the GEMM fragment read ONE ds_read_b128 per (row, kspair) with even
// 8-lanes-per-slot bank distribution (conflict-free at the b128 floor).
__device__ __forceinline__ int perm16(int u8) {
    int ks = u8 >> 2, kg = u8 & 3;
    return (ks >> 1) * 8 + kg * 2 + (ks & 1);
}

// ===========================================================================
// FAST PATH kernel 1: f32 -> fp8 e4m3 (permuted k-order) + norms of the
// QUANTIZED values (so d2 = ||q_i - q_j||^2 is exact for quantized vectors).
// One block per row: t<128 -> 8 x elems each (8B store), t in [128,192) -> y.
// ===========================================================================
__global__ void __launch_bounds__(192)
convert_fp8(const float* __restrict__ x, const float* __restrict__ y,
            u64* __restrict__ xq, u64* __restrict__ yq,
            float* __restrict__ sqx, float* __restrict__ sqy) {
    __shared__ float part[2];
    const int row = blockIdx.x;
    const int t   = threadIdx.x;
    const int lane = t & 63;
    const int wid  = t >> 6;

    float nrm = 0.f;
    if (t < 128) {
        const float4* p = (const float4*)(x + (size_t)row * D_X + t * 8);
        float4 f0 = p[0], f1 = p[1];
        float e[8] = {f0.x, f0.y, f0.z, f0.w, f1.x, f1.y, f1.z, f1.w};
        u64 w = 0;
#pragma unroll
        for (int i = 0; i < 8; ++i) {
            __hip_fp8_e4m3 q(e[i]);                  // RNE + saturate (OCP)
            float b = (float)q;
            nrm = fmaf(b, b, nrm);
            w |= (u64)q.__x << (8 * i);
        }
        xq[(size_t)row * 128 + (t & ~15) + perm16(t & 15)] = w;
    } else {
        int o = t - 128;                             // 0..63
        const float4* p = (const float4*)(y + (size_t)row * D_Y + o * 8);
        float4 f0 = p[0], f1 = p[1];
        float e[8] = {f0.x, f0.y, f0.z, f0.w, f1.x, f1.y, f1.z, f1.w};
        u64 w = 0;
#pragma unroll
        for (int i = 0; i < 8; ++i) {
            __hip_fp8_e4m3 q(e[i]);
            float b = (float)q;
            nrm = fmaf(b, b, nrm);
            w |= (u64)q.__x << (8 * i);
        }
        yq[(size_t)row * 64 + (o & ~15) + perm16(o & 15)] = w;
    }
#pragma unroll
    for (int off = 32; off > 0; off >>= 1)
        nrm += __shfl_down(nrm, off, 64);
    if (lane == 0) {
        if (wid < 2) part[wid] = nrm;
        else         sqy[row] = nrm;
    }
    __syncthreads();
    if (t == 0) sqx[row] = part[0] + part[1];
}

// ===========================================================================
// FAST PATH kernel 2: fused fp8 Gram(x), Gram(y) -> masked loss.
// R8 sync skeleton: 64^2 tiles, combined A|B LDS tile [128 rows][8 x 16B]
// (16 KB), BK=128 fp8 -> 12 steps, 2 buffers, depth-2 counted vmcnt(4),
// 4 blocks/CU. Fragment reads are swizzled ds_read_b128 (conflict-free).
// ===========================================================================

// Issue one step's staging. LDS dest LINEAR; XOR slot swizzle computed in the
// per-lane GLOBAL source address (rule #21). 4 gload_lds/thread = 4 vmcnt.
__device__ __forceinline__ void issue8(int s,
                                       const u16x8* __restrict__ xq,
                                       const u16x8* __restrict__ yq,
                                       int iA, int iB,
                                       u16x8* dst, int tid) {
    const int wid = tid >> 6, lane = tid & 63;
    const u16x8* src; int rs, k0;
    if (s < NSX8) { src = xq; rs = XS8; k0 = s * 8; }
    else          { src = yq; rs = YS8; k0 = (s - NSX8) * 8; }
#pragma unroll
    for (int it = 0; it < 4; ++it) {
        int u   = it * 256 + wid * 64;   // wave-uniform LDS slot base
        int ul  = u + lane;
        int row = ul >> 3;               // 0..127
        int st  = ul & 7;
        int lg  = st ^ (row & 7);
        int grow = (row < 64 ? iA + row : iB + row - 64);
        const u16x8* g = src + (size_t)grow * rs + k0 + lg;
        __builtin_amdgcn_global_load_lds(
            (const uint32_t __attribute__((address_space(1)))*)g,
            (uint32_t __attribute__((address_space(3)))*)(dst + u), 16, 0, 0);
    }
}

// One b128 fragment read: 16B chunk c = t*4+kgrp (ks-pair {2t,2t+1}) of row.
__device__ __forceinline__ u64x2 ldsfrag2(const u16x8* T, int row, int c) {
    int slot = c ^ (row & 7);
    return __builtin_bit_cast(u64x2, T[row * 8 + slot]);
}

// One pipeline step (depth-2 counted; W never 0 until the last step).
#define GSTEP8(BUF, T, ACC, W)                                             \
    {                                                                      \
        asm volatile("s_waitcnt vmcnt(" #W ")" ::: "memory");              \
        __builtin_amdgcn_s_barrier();                                      \
        u64x2 fa[2][2], fb[2][2];   /* [kspair][frag] */                   \
        _Pragma("unroll")                                                  \
        for (int t2 = 0; t2 < 2; ++t2) {                                   \
            _Pragma("unroll")                                              \
            for (int m = 0; m < 2; ++m)                                    \
                fa[t2][m] = ldsfrag2(BUF, wr * 32 + m * 16 + lrow,         \
                                     t2 * 4 + kgrp);                       \
            _Pragma("unroll")                                              \
            for (int n = 0; n < 2; ++n)                                    \
                fb[t2][n] = ldsfrag2(BUF, 64 + wc * 32 + n * 16 + lrow,    \
                                     t2 * 4 + kgrp);                       \
        }                                                                  \
        asm volatile("s_waitcnt lgkmcnt(0)" ::: "memory");                 \
        __builtin_amdgcn_s_barrier();                                      \
        issue8((T) + 2, xq, yq, iA, iB, BUF, tid);                         \
        __builtin_amdgcn_s_setprio(1);                                     \
        _Pragma("unroll")                                                  \
        for (int t2 = 0; t2 < 2; ++t2)                                     \
            _Pragma("unroll")                                              \
            for (int h = 0; h < 2; ++h)                                    \
                _Pragma("unroll")                                          \
                for (int m = 0; m < 2; ++m)                                \
                    _Pragma("unroll")                                      \
                    for (int n = 0; n < 2; ++n)                            \
                        ACC[m][n] =                                        \
                            __builtin_amdgcn_mfma_f32_16x16x32_fp8_fp8(    \
                                (long)fa[t2][m][h], (long)fb[t2][n][h],    \
                                ACC[m][n], 0, 0, 0);                       \
        __builtin_amdgcn_s_setprio(0);                                     \
    }
#define GSTEP8_NOISSUE(BUF, ACC, W)                                        \
    {                                                                      \
        asm volatile("s_waitcnt vmcnt(" #W ")" ::: "memory");              \
        __builtin_amdgcn_s_barrier();                                      \
        u64x2 fa[2][2], fb[2][2];                                          \
        _Pragma("unroll")                                                  \
        for (int t2 = 0; t2 < 2; ++t2) {                                   \
            _Pragma("unroll")                                              \
            for (int m = 0; m < 2; ++m)                                    \
                fa[t2][m] = ldsfrag2(BUF, wr * 32 + m * 16 + lrow,         \
                                     t2 * 4 + kgrp);                       \
            _Pragma("unroll")                                              \
            for (int n = 0; n < 2; ++n)                                    \
                fb[t2][n] = ldsfrag2(BUF, 64 + wc * 32 + n * 16 + lrow,    \
                                     t2 * 4 + kgrp);                       \
        }                                                                  \
        __builtin_amdgcn_s_setprio(1);                                     \
        _Pragma("unroll")                                                  \
        for (int t2 = 0; t2 < 2; ++t2)                                     \
            _Pragma("unroll")                                              \
            for (int h = 0; h < 2; ++h)                                    \
                _Pragma("unroll")                                          \
                for (int m = 0; m < 2; ++m)                                \
                    _Pragma("unroll")                                      \
                    for (int n = 0; n < 2; ++n)                            \
                        ACC[m][n] =                                        \
                            __builtin_amdgcn_mfma_f32_16x16x32_fp8_fp8(    \
                                (long)fa[t2][m][h], (long)fb[t2][n][h],    \
                                ACC[m][n], 0, 0, 0);                       \
        __builtin_amdgcn_s_setprio(0);                                     \
    }

__global__ void __launch_bounds__(256, 4)
gram_fp8(const u16x8* __restrict__ xq, const u16x8* __restrict__ yq,
         const float* __restrict__ sqx, const float* __restrict__ sqy,
         float* __restrict__ out) {
    __shared__ u16x8 T0[1024], T1[1024];   // 2 x 16 KB combined A|B tiles
    __shared__ float snxA[BM2], snxB[BM2], snyA[BM2], snyB[BM2];
    __shared__ float wsum[4];

    const int tid  = threadIdx.x;
    const int lane = tid & 63;
    const int wid  = tid >> 6;
    const int wr   = wid >> 1;
    const int wc   = wid & 1;
    const int lrow = lane & 15;
    const int kgrp = lane >> 4;

    // T1: chunked XCD swizzle (bijective: NBLK2 % 8 == 0).
    int sb = (blockIdx.x & 7) * (NBLK2 / 8) + (blockIdx.x >> 3);

    // triangular tile mapping
    int t0 = sb, bi = 0;
    while (t0 >= NT2 - bi) { t0 -= NT2 - bi; ++bi; }
    const int bj = bi + t0;
    const int iA = bi * BM2;
    const int iB = bj * BM2;
    const bool diag = (bi == bj);

    if (tid < BM2) {
        snxA[tid] = sqx[iA + tid];
        snyA[tid] = sqy[iA + tid];
        snxB[tid] = sqx[iB + tid];
        snyB[tid] = sqy[iB + tid];
    }

    f32x4 accX[2][2] = {};
    f32x4 accY[2][2] = {};

    // prologue: pre-issue steps 0,1 (8 loads in flight; no drain)
    issue8(0, xq, yq, iA, iB, T0, tid);
    issue8(1, xq, yq, iA, iB, T1, tid);

    // X phase: steps 0..7 (BK=128)
    for (int g = 0; g < 4; ++g) {
        GSTEP8(T0, 2 * g,     accX, 4);   // issues 2g+2
        GSTEP8(T1, 2 * g + 1, accX, 4);   // issues 2g+3 (g=3 -> 9, Y ok)
    }
    // Y phase: steps 8,9 with issues 10,11
    GSTEP8(T0, 8, accY, 4);
    GSTEP8(T1, 9, accY, 4);
    // peeled tail: steps 10,11
    GSTEP8_NOISSUE(T0, accY, 4);          // step 10 (batch 11 in flight)
    GSTEP8_NOISSUE(T1, accY, 0);          // step 11 (full drain)

    // Epilogue: C/D layout col=lane&15, row=(lane>>4)*4+reg (m89, dtype-indep)
    float local = 0.f;
#pragma unroll
    for (int m = 0; m < 2; ++m) {
#pragma unroll
        for (int n = 0; n < 2; ++n) {
            int col   = wc * 32 + n * 16 + lrow;
            float sxj = snxB[col];
            float syj = snyB[col];
#pragma unroll
            for (int r = 0; r < 4; ++r) {
                int rowi  = wr * 32 + m * 16 + kgrp * 4 + r;
                float d2x = snxA[rowi] + sxj - 2.f * accX[m][n][r];
                float dxv = sqrtf(fmaxf(d2x, 1e-12f));
                float d2y = snyA[rowi] + syj - 2.f * accY[m][n][r];
                float dyv = sqrtf(fmaxf(d2y, 1e-12f));
                int gi = iA + rowi, gj = iB + col;
                bool keep = (gi != gj) && (dxv <= EPS_THR);
                float contrib = __expf(-dxv * SIGMA_INV) * dyv;
                local += keep ? contrib : 0.f;
            }
        }
    }
    if (!diag) local *= 2.f;

#pragma unroll
    for (int off = 32; off > 0; off >>= 1)
        local += __shfl_down(local, off, 64);
    if (lane == 0) wsum[wid] = local;
    __syncthreads();
    if (tid == 0)
        atomicAdd(out, wsum[0] + wsum[1] + wsum[2] + wsum[3]);
}

// ===========================================================================
// FALLBACK PATH (bf16, round-2 structure) — used only if ws too small.
// ===========================================================================
__global__ void norms_kernel_fb(const float* __restrict__ x,
                                const float* __restrict__ y,
                                float* __restrict__ sqx,
                                float* __restrict__ sqy) {
    int row = blockIdx.x;
    int t   = threadIdx.x;
    const float4* xr = (const float4*)(x + (size_t)row * D_X);
    float sx = 0.f;
#pragma unroll
    for (int i = 0; i < D_X / 4 / 64; ++i) {
        float4 v = xr[t + i * 64];
        sx += v.x * v.x + v.y * v.y + v.z * v.z + v.w * v.w;
    }
    const float4* yr = (const float4*)(y + (size_t)row * D_Y);
    float sy = 0.f;
#pragma unroll
    for (int i = 0; i < D_Y / 4 / 64; ++i) {
        float4 v = yr[t + i * 64];
        sy += v.x * v.x + v.y * v.y + v.z * v.z + v.w * v.w;
    }
#pragma unroll
    for (int off = 32; off > 0; off >>= 1) {
        sx += __shfl_down(sx, off, 64);
        sy += __shfl_down(sy, off, 64);
    }
    if (t == 0) { sqx[row] = sx; sqy[row] = sy; }
}

__device__ __forceinline__ void stage_tile_fb(const float* __restrict__ src, int ld,
                                              int base_row, int k0,
                                              u16x8* __restrict__ dst, int tid) {
#pragma unroll
    for (int it = 0; it < 2; ++it) {
        int u   = tid + it * 256;
        int row = u >> 2;
        int q   = u & 3;
        const float4* p = (const float4*)(src + (size_t)(base_row + row) * ld + k0 + q * 16);
        float4 f0 = p[0], f1 = p[1], f2 = p[2], f3 = p[3];
        u16x8 lo, hi;
        lo[0] = f32_to_bf16_bits(f0.x); lo[1] = f32_to_bf16_bits(f0.y);
        lo[2] = f32_to_bf16_bits(f0.z); lo[3] = f32_to_bf16_bits(f0.w);
        lo[4] = f32_to_bf16_bits(f1.x); lo[5] = f32_to_bf16_bits(f1.y);
        lo[6] = f32_to_bf16_bits(f1.z); lo[7] = f32_to_bf16_bits(f1.w);
        hi[0] = f32_to_bf16_bits(f2.x); hi[1] = f32_to_bf16_bits(f2.y);
        hi[2] = f32_to_bf16_bits(f2.z); hi[3] = f32_to_bf16_bits(f2.w);
        hi[4] = f32_to_bf16_bits(f3.x); hi[5] = f32_to_bf16_bits(f3.y);
        hi[6] = f32_to_bf16_bits(f3.z); hi[7] = f32_to_bf16_bits(f3.w);
        int swz = row & 7;
        dst[row * 8 + ((2 * q) ^ swz)]     = lo;
        dst[row * 8 + ((2 * q + 1) ^ swz)] = hi;
    }
}

__device__ __forceinline__ void mfma16_fb(const bf16x8 a[4], const bf16x8 b[4],
                                          f32x4 acc[4][4]) {
#pragma unroll
    for (int m = 0; m < 4; ++m)
#pragma unroll
        for (int n = 0; n < 4; ++n)
            acc[m][n] = __builtin_amdgcn_mfma_f32_16x16x32_bf16(
                a[m], b[n], acc[m][n], 0, 0, 0);
}

__device__ __forceinline__ void load_frags_fb(const u16x8* As_, const u16x8* Bs_,
                                              int wr, int wc, int lrow, int kgrp,
                                              bf16x8 a[2][4], bf16x8 b[2][4]) {
#pragma unroll
    for (int ks = 0; ks < 2; ++ks) {
#pragma unroll
        for (int m = 0; m < 4; ++m) {
            int row  = wr * 64 + m * 16 + lrow;
            int slot = (ks * 4 + kgrp) ^ (row & 7);
            a[ks][m] = __builtin_bit_cast(bf16x8, As_[row * 8 + slot]);
        }
#pragma unroll
        for (int n = 0; n < 4; ++n) {
            int row  = wc * 64 + n * 16 + lrow;
            int slot = (ks * 4 + kgrp) ^ (row & 7);
            b[ks][n] = __builtin_bit_cast(bf16x8, Bs_[row * 8 + slot]);
        }
    }
}

__global__ void __launch_bounds__(256, 2)
graph_loss_fb(const float* __restrict__ x, const float* __restrict__ y,
              const float* __restrict__ sqx, const float* __restrict__ sqy,
              float* __restrict__ out) {
    __shared__ u16x8 As[BM * 8];
    __shared__ u16x8 Bs[BM * 8];
    __shared__ float snxA[BM], snxB[BM], snyA[BM], snyB[BM];
    __shared__ float wsum[4];

    const int tid  = threadIdx.x;
    const int lane = tid & 63;
    const int wid  = tid >> 6;
    const int wr   = wid >> 1;
    const int wc   = wid & 1;
    const int lrow = lane & 15;
    const int kgrp = lane >> 4;

    int t = blockIdx.x, bi = 0;
    while (t >= NT - bi) { t -= NT - bi; ++bi; }
    const int bj = bi + t;
    const int iA = bi * BM;
    const int iB = bj * BM;

    if (tid < BM) {
        snxA[tid] = sqx[iA + tid];
        snyA[tid] = sqy[iA + tid];
        snxB[tid] = sqx[iB + tid];
        snyB[tid] = sqy[iB + tid];
    }

    f32x4 accX[4][4] = {};
    f32x4 accY[4][4] = {};
    bf16x8 a[2][4], b[2][4];

    for (int kt = 0; kt < D_X / 64; ++kt) {
        __syncthreads();
        stage_tile_fb(x, D_X, iA, kt * 64, As, tid);
        stage_tile_fb(x, D_X, iB, kt * 64, Bs, tid);
        __syncthreads();
        load_frags_fb(As, Bs, wr, wc, lrow, kgrp, a, b);
#pragma unroll
        for (int ks = 0; ks < 2; ++ks) mfma16_fb(a[ks], b[ks], accX);
    }
    for (int kt = 0; kt < D_Y / 64; ++kt) {
        __syncthreads();
        stage_tile_fb(y, D_Y, iA, kt * 64, As, tid);
        stage_tile_fb(y, D_Y, iB, kt * 64, Bs, tid);
        __syncthreads();
        load_frags_fb(As, Bs, wr, wc, lrow, kgrp, a, b);
#pragma unroll
        for (int ks = 0; ks < 2; ++ks) mfma16_fb(a[ks], b[ks], accY);
    }

    float local = 0.f;
#pragma unroll
    for (int m = 0; m < 4; ++m) {
#pragma unroll
        for (int n = 0; n < 4; ++n) {
            int col   = wc * 64 + n * 16 + lrow;
            float sxj = snxB[col];
            float syj = snyB[col];
#pragma unroll
            for (int r = 0; r < 4; ++r) {
                int rowi  = wr * 64 + m * 16 + kgrp * 4 + r;
                float d2x = snxA[rowi] + sxj - 2.f * accX[m][n][r];
                float dxv = sqrtf(fmaxf(d2x, 1e-12f));
                float d2y = snyA[rowi] + syj - 2.f * accY[m][n][r];
                float dyv = sqrtf(fmaxf(d2y, 1e-12f));
                int gi = iA + rowi, gj = iB + col;
                bool keep = (gi != gj) && (dxv <= EPS_THR);
                float contrib = __expf(-dxv * SIGMA_INV) * dyv;
                local += keep ? contrib : 0.f;
            }
        }
    }
    if (bi != bj) local *= 2.f;

#pragma unroll
    for (int off = 32; off > 0; off >>= 1)
        local += __shfl_down(local, off, 64);
    if (lane == 0) wsum[wid] = local;
    __syncthreads();
    if (tid == 0)
        atomicAdd(out, wsum[0] + wsum[1] + wsum[2] + wsum[3]);
}

// ===========================================================================
extern "C" void kernel_launch(void* const* d_in, const int* in_sizes, int n_in,
                              void* d_out, int out_size, void* d_ws, size_t ws_size,
                              hipStream_t stream) {
    const float* x = (const float*)d_in[0];
    const float* y = (const float*)d_in[1];
    float* out = (float*)d_out;

    hipMemsetAsync(d_out, 0, sizeof(float) * (size_t)out_size, stream);

    const size_t xq_bytes = (size_t)BATCH * D_X;        // 4 MB fp8
    const size_t yq_bytes = (size_t)BATCH * D_Y;        // 2 MB fp8
    const size_t sq_bytes = 2 * (size_t)BATCH * sizeof(float);
    const size_t need = xq_bytes + yq_bytes + sq_bytes;

    if (ws_size >= need) {
        u64*   xq  = (u64*)d_ws;
        u64*   yq  = (u64*)((char*)d_ws + xq_bytes);
        float* sqx = (float*)((char*)d_ws + xq_bytes + yq_bytes);
        float* sqy = sqx + BATCH;
        convert_fp8<<<BATCH, 192, 0, stream>>>(x, y, xq, yq, sqx, sqy);
        gram_fp8<<<NBLK2, 256, 0, stream>>>((const u16x8*)xq, (const u16x8*)yq,
                                            sqx, sqy, out);
    } else {
        float* sqx = (float*)d_ws;
        float* sqy = sqx + BATCH;
        norms_kernel_fb<<<BATCH, 64, 0, stream>>>(x, y, sqx, sqy);
        graph_loss_fb<<<NBLK, 256, 0, stream>>>(x, y, sqx, sqy, out);
    }
}

// Round 13
// 60.526 us; speedup vs baseline: 1.6217x; 1.0021x over previous
//
#include <hip/hip_runtime.h>
#include <hip/hip_bf16.h>
#include <hip/hip_fp8.h>
#include <stdint.h>

// Problem constants (from reference)
#define BATCH 4096
#define D_X   1024
#define D_Y   512

constexpr float SIGMA_INV = 0.1f;    // 1/10.0
constexpr float EPS_THR   = 46.0f;

// ---- fast path: fp8 e4m3, 64x64 triangular tiles ----
constexpr int BM2   = 64;
constexpr int NT2   = BATCH / BM2;           // 64 tile-rows
constexpr int NBLK2 = NT2 * (NT2 + 1) / 2;   // 2080 (2080 % 8 == 0)
constexpr int XS8   = D_X / 16;              // 64 16B slots per fp8 x row
constexpr int YS8   = D_Y / 16;              // 32 slots per fp8 y row
constexpr int NSX8  = D_X / 128;             // 8 X K-steps (BK=128)

// ---- fallback tiling (128^2 bf16, round-2 structure) ----
constexpr int BM = 128;
constexpr int NT = BATCH / BM;
constexpr int NBLK = NT * (NT + 1) / 2;

typedef __bf16 bf16x8 __attribute__((ext_vector_type(8)));
typedef float  f32x4  __attribute__((ext_vector_type(4)));
typedef unsigned short u16x8 __attribute__((ext_vector_type(8)));
typedef unsigned long long u64;
typedef u64 u64x2 __attribute__((ext_vector_type(2)));

__device__ __forceinline__ unsigned short f32_to_bf16_bits(float f) {
    unsigned int u = __builtin_bit_cast(unsigned int, f);
    unsigned int r = (u + 0x7FFFu + ((u >> 16) & 1u)) >> 16;  // RNE
    return (unsigned short)r;
}

// k-unit permutation: logical u8 (ks = u8>>2, kgrp = u8&3) -> stored pos so
// that 16B chunk c = (ks>>1)*4 + kgrp holds the ks-pair {2t,2t+1} of kgrp.
// Makes the GEMM fragment read ONE ds_read_b128 per (row, kspair) with even
// 8-lanes-per-slot bank distribution (conflict-free at the b128 floor).
__device__ __forceinline__ int perm16(int u8) {
    int ks = u8 >> 2, kg = u8 & 3;
    return (ks >> 1) * 8 + kg * 2 + (ks & 1);
}

// ===========================================================================
// FAST PATH kernel 1: f32 -> fp8 e4m3 (permuted k-order) + norms of the
// QUANTIZED values (so d2 = ||q_i - q_j||^2 is exact for quantized vectors).
// ===========================================================================
__global__ void __launch_bounds__(192)
convert_fp8(const float* __restrict__ x, const float* __restrict__ y,
            u64* __restrict__ xq, u64* __restrict__ yq,
            float* __restrict__ sqx, float* __restrict__ sqy) {
    __shared__ float part[2];
    const int row = blockIdx.x;
    const int t   = threadIdx.x;
    const int lane = t & 63;
    const int wid  = t >> 6;

    float nrm = 0.f;
    if (t < 128) {
        const float4* p = (const float4*)(x + (size_t)row * D_X + t * 8);
        float4 f0 = p[0], f1 = p[1];
        float e[8] = {f0.x, f0.y, f0.z, f0.w, f1.x, f1.y, f1.z, f1.w};
        u64 w = 0;
#pragma unroll
        for (int i = 0; i < 8; ++i) {
            __hip_fp8_e4m3 q(e[i]);                  // RNE + saturate (OCP)
            float b = (float)q;
            nrm = fmaf(b, b, nrm);
            w |= (u64)q.__x << (8 * i);
        }
        xq[(size_t)row * 128 + (t & ~15) + perm16(t & 15)] = w;
    } else {
        int o = t - 128;                             // 0..63
        const float4* p = (const float4*)(y + (size_t)row * D_Y + o * 8);
        float4 f0 = p[0], f1 = p[1];
        float e[8] = {f0.x, f0.y, f0.z, f0.w, f1.x, f1.y, f1.z, f1.w};
        u64 w = 0;
#pragma unroll
        for (int i = 0; i < 8; ++i) {
            __hip_fp8_e4m3 q(e[i]);
            float b = (float)q;
            nrm = fmaf(b, b, nrm);
            w |= (u64)q.__x << (8 * i);
        }
        yq[(size_t)row * 64 + (o & ~15) + perm16(o & 15)] = w;
    }
#pragma unroll
    for (int off = 32; off > 0; off >>= 1)
        nrm += __shfl_down(nrm, off, 64);
    if (lane == 0) {
        if (wid < 2) part[wid] = nrm;
        else         sqy[row] = nrm;
    }
    __syncthreads();
    if (t == 0) sqx[row] = part[0] + part[1];
}

// ===========================================================================
// FAST PATH kernel 2: fused fp8 Gram(x), Gram(y) -> masked loss.
// R11 sync skeleton: 64^2 tiles, combined A|B LDS tile [128 rows][8x16B]
// (16 KB), BK=128 fp8 -> 12 steps, 2 buffers, depth-2 counted vmcnt(4).
// R13: per-lane base pointers computed ONCE; step offset applied as POINTER
// ARITHMETIC on the global side (global_load_lds imm-offset arg MUST stay 0:
// the HW applies that immediate to BOTH global and LDS addresses -> the R12
// corruption).
// ===========================================================================

// One b128 fragment read: 16B chunk c = t2*4+kgrp (ks-pair {2t2,2t2+1}).
__device__ __forceinline__ u64x2 ldsfrag2(const u16x8* T, int row, int c) {
    int slot = c ^ (row & 7);
    return __builtin_bit_cast(u64x2, T[row * 8 + slot]);
}

// Issue one step's 4 global_load_lds: per-lane BASE[it] + byte OFF via
// pointer arithmetic; intrinsic offset arg = 0 ALWAYS.
#define ISSUE(DST, BASE, OFF)                                              \
    {                                                                      \
        _Pragma("unroll")                                                  \
        for (int it = 0; it < 4; ++it)                                     \
            __builtin_amdgcn_global_load_lds(                              \
                (const uint32_t __attribute__((address_space(1)))*)(BASE[it] + (OFF)), \
                (uint32_t __attribute__((address_space(3)))*)((DST) + it * 256 + wid * 64), \
                16, 0, 0);                                                 \
    }

#define FRAGS_READ(BUF)                                                    \
        u64x2 fa[2][2], fb[2][2];   /* [kspair][frag] */                   \
        _Pragma("unroll")                                                  \
        for (int t2 = 0; t2 < 2; ++t2) {                                   \
            _Pragma("unroll")                                              \
            for (int m = 0; m < 2; ++m)                                    \
                fa[t2][m] = ldsfrag2(BUF, wr * 32 + m * 16 + lrow,         \
                                     t2 * 4 + kgrp);                       \
            _Pragma("unroll")                                              \
            for (int n = 0; n < 2; ++n)                                    \
                fb[t2][n] = ldsfrag2(BUF, 64 + wc * 32 + n * 16 + lrow,    \
                                     t2 * 4 + kgrp);                       \
        }

#define FRAGS_MFMA(ACC)                                                    \
        __builtin_amdgcn_s_setprio(1);                                     \
        _Pragma("unroll")                                                  \
        for (int t2 = 0; t2 < 2; ++t2)                                     \
            _Pragma("unroll")                                              \
            for (int h = 0; h < 2; ++h)                                    \
                _Pragma("unroll")                                          \
                for (int m = 0; m < 2; ++m)                                \
                    _Pragma("unroll")                                      \
                    for (int n = 0; n < 2; ++n)                            \
                        ACC[m][n] =                                        \
                            __builtin_amdgcn_mfma_f32_16x16x32_fp8_fp8(    \
                                (long)fa[t2][m][h], (long)fb[t2][n][h],    \
                                ACC[m][n], 0, 0, 0);                       \
        __builtin_amdgcn_s_setprio(0);

// One pipeline step (depth-2 counted; W never 0 until the last step).
#define GSTEP(BUF, ACC, W, IBASE, IOFF)                                    \
    {                                                                      \
        asm volatile("s_waitcnt vmcnt(" #W ")" ::: "memory");              \
        __builtin_amdgcn_s_barrier();                                      \
        FRAGS_READ(BUF)                                                    \
        asm volatile("s_waitcnt lgkmcnt(0)" ::: "memory");                 \
        __builtin_amdgcn_s_barrier();                                      \
        ISSUE(BUF, IBASE, IOFF)                                            \
        FRAGS_MFMA(ACC)                                                    \
    }
#define GSTEP_NOISSUE(BUF, ACC, W)                                         \
    {                                                                      \
        asm volatile("s_waitcnt vmcnt(" #W ")" ::: "memory");              \
        __builtin_amdgcn_s_barrier();                                      \
        FRAGS_READ(BUF)                                                    \
        FRAGS_MFMA(ACC)                                                    \
    }

__global__ void __launch_bounds__(256, 4)
gram_fp8(const u16x8* __restrict__ xq, const u16x8* __restrict__ yq,
         const float* __restrict__ sqx, const float* __restrict__ sqy,
         float* __restrict__ out) {
    __shared__ u16x8 T0[1024], T1[1024];   // 2 x 16 KB combined A|B tiles
    __shared__ float snxA[BM2], snxB[BM2], snyA[BM2], snyB[BM2];
    __shared__ float wsum[4];

    const int tid  = threadIdx.x;
    const int lane = tid & 63;
    const int wid  = tid >> 6;
    const int wr   = wid >> 1;
    const int wc   = wid & 1;
    const int lrow = lane & 15;
    const int kgrp = lane >> 4;

    // T1: chunked XCD swizzle (bijective: NBLK2 % 8 == 0).
    int sb = (blockIdx.x & 7) * (NBLK2 / 8) + (blockIdx.x >> 3);

    // triangular tile mapping
    int t0 = sb, bi = 0;
    while (t0 >= NT2 - bi) { t0 -= NT2 - bi; ++bi; }
    const int bj = bi + t0;
    const int iA = bi * BM2;
    const int iB = bj * BM2;
    const bool diag = (bi == bj);

    if (tid < BM2) {
        snxA[tid] = sqx[iA + tid];
        snyA[tid] = sqy[iA + tid];
        snxB[tid] = sqx[iB + tid];
        snyB[tid] = sqy[iB + tid];
    }

    // Per-lane staging base pointers (fixed for the whole kernel).
    // Lane ul = it*256 + wid*64 + lane maps to (row, stored-slot st);
    // swizzle folded into the base: logical slot lg = st ^ (row&7).
    const char* gx[4];
    const char* gy[4];
#pragma unroll
    for (int it = 0; it < 4; ++it) {
        int ul   = it * 256 + wid * 64 + lane;
        int row  = ul >> 3;
        int st   = ul & 7;
        int lg   = st ^ (row & 7);
        int grow = (row < 64 ? iA + row : iB + row - 64);
        gx[it] = (const char*)xq + (size_t)grow * (XS8 * 16) + lg * 16;
        gy[it] = (const char*)yq + (size_t)grow * (YS8 * 16) + lg * 16;
    }

    f32x4 accX[2][2] = {};
    f32x4 accY[2][2] = {};

    // prologue: pre-issue steps 0,1 (8 loads in flight; no drain)
    ISSUE(T0, gx, 0)
    ISSUE(T1, gx, 128)

    // 12 steps, hand-unrolled; step s stages bytes s*128 past the base.
    GSTEP(T0, accX, 4, gx, 256)   // s=0,  issues s=2
    GSTEP(T1, accX, 4, gx, 384)   // s=1,  issues s=3
    GSTEP(T0, accX, 4, gx, 512)   // s=2,  issues s=4
    GSTEP(T1, accX, 4, gx, 640)   // s=3,  issues s=5
    GSTEP(T0, accX, 4, gx, 768)   // s=4,  issues s=6
    GSTEP(T1, accX, 4, gx, 896)   // s=5,  issues s=7
    GSTEP(T0, accX, 4, gy, 0)     // s=6,  issues s=8  (first Y step)
    GSTEP(T1, accX, 4, gy, 128)   // s=7,  issues s=9
    GSTEP(T0, accY, 4, gy, 256)   // s=8,  issues s=10
    GSTEP(T1, accY, 4, gy, 384)   // s=9,  issues s=11
    GSTEP_NOISSUE(T0, accY, 4)    // s=10 (batch 11 in flight)
    GSTEP_NOISSUE(T1, accY, 0)    // s=11 (full drain)

    // Epilogue: C/D layout col=lane&15, row=(lane>>4)*4+reg (m89, dtype-indep)
    float local = 0.f;
#pragma unroll
    for (int m = 0; m < 2; ++m) {
#pragma unroll
        for (int n = 0; n < 2; ++n) {
            int col   = wc * 32 + n * 16 + lrow;
            float sxj = snxB[col];
            float syj = snyB[col];
#pragma unroll
            for (int r = 0; r < 4; ++r) {
                int rowi  = wr * 32 + m * 16 + kgrp * 4 + r;
                float d2x = snxA[rowi] + sxj - 2.f * accX[m][n][r];
                float dxv = sqrtf(fmaxf(d2x, 1e-12f));
                float d2y = snyA[rowi] + syj - 2.f * accY[m][n][r];
                float dyv = sqrtf(fmaxf(d2y, 1e-12f));
                int gi = iA + rowi, gj = iB + col;
                bool keep = (gi != gj) && (dxv <= EPS_THR);
                float contrib = __expf(-dxv * SIGMA_INV) * dyv;
                local += keep ? contrib : 0.f;
            }
        }
    }
    if (!diag) local *= 2.f;

#pragma unroll
    for (int off = 32; off > 0; off >>= 1)
        local += __shfl_down(local, off, 64);
    if (lane == 0) wsum[wid] = local;
    __syncthreads();
    if (tid == 0)
        atomicAdd(out, wsum[0] + wsum[1] + wsum[2] + wsum[3]);
}

// ===========================================================================
// FALLBACK PATH (bf16, round-2 structure) — used only if ws too small.
// ===========================================================================
__global__ void norms_kernel_fb(const float* __restrict__ x,
                                const float* __restrict__ y,
                                float* __restrict__ sqx,
                                float* __restrict__ sqy) {
    int row = blockIdx.x;
    int t   = threadIdx.x;
    const float4* xr = (const float4*)(x + (size_t)row * D_X);
    float sx = 0.f;
#pragma unroll
    for (int i = 0; i < D_X / 4 / 64; ++i) {
        float4 v = xr[t + i * 64];
        sx += v.x * v.x + v.y * v.y + v.z * v.z + v.w * v.w;
    }
    const float4* yr = (const float4*)(y + (size_t)row * D_Y);
    float sy = 0.f;
#pragma unroll
    for (int i = 0; i < D_Y / 4 / 64; ++i) {
        float4 v = yr[t + i * 64];
        sy += v.x * v.x + v.y * v.y + v.z * v.z + v.w * v.w;
    }
#pragma unroll
    for (int off = 32; off > 0; off >>= 1) {
        sx += __shfl_down(sx, off, 64);
        sy += __shfl_down(sy, off, 64);
    }
    if (t == 0) { sqx[row] = sx; sqy[row] = sy; }
}

__device__ __forceinline__ void stage_tile_fb(const float* __restrict__ src, int ld,
                                              int base_row, int k0,
                                              u16x8* __restrict__ dst, int tid) {
#pragma unroll
    for (int it = 0; it < 2; ++it) {
        int u   = tid + it * 256;
        int row = u >> 2;
        int q   = u & 3;
        const float4* p = (const float4*)(src + (size_t)(base_row + row) * ld + k0 + q * 16);
        float4 f0 = p[0], f1 = p[1], f2 = p[2], f3 = p[3];
        u16x8 lo, hi;
        lo[0] = f32_to_bf16_bits(f0.x); lo[1] = f32_to_bf16_bits(f0.y);
        lo[2] = f32_to_bf16_bits(f0.z); lo[3] = f32_to_bf16_bits(f0.w);
        lo[4] = f32_to_bf16_bits(f1.x); lo[5] = f32_to_bf16_bits(f1.y);
        lo[6] = f32_to_bf16_bits(f1.z); lo[7] = f32_to_bf16_bits(f1.w);
        hi[0] = f32_to_bf16_bits(f2.x); hi[1] = f32_to_bf16_bits(f2.y);
        hi[2] = f32_to_bf16_bits(f2.z); hi[3] = f32_to_bf16_bits(f2.w);
        hi[4] = f32_to_bf16_bits(f3.x); hi[5] = f32_to_bf16_bits(f3.y);
        hi[6] = f32_to_bf16_bits(f3.z); hi[7] = f32_to_bf16_bits(f3.w);
        int swz = row & 7;
        dst[row * 8 + ((2 * q) ^ swz)]     = lo;
        dst[row * 8 + ((2 * q + 1) ^ swz)] = hi;
    }
}

__device__ __forceinline__ void mfma16_fb(const bf16x8 a[4], const bf16x8 b[4],
                                          f32x4 acc[4][4]) {
#pragma unroll
    for (int m = 0; m < 4; ++m)
#pragma unroll
        for (int n = 0; n < 4; ++n)
            acc[m][n] = __builtin_amdgcn_mfma_f32_16x16x32_bf16(
                a[m], b[n], acc[m][n], 0, 0, 0);
}

__device__ __forceinline__ void load_frags_fb(const u16x8* As_, const u16x8* Bs_,
                                              int wr, int wc, int lrow, int kgrp,
                                              bf16x8 a[2][4], bf16x8 b[2][4]) {
#pragma unroll
    for (int ks = 0; ks < 2; ++ks) {
#pragma unroll
        for (int m = 0; m < 4; ++m) {
            int row  = wr * 64 + m * 16 + lrow;
            int slot = (ks * 4 + kgrp) ^ (row & 7);
            a[ks][m] = __builtin_bit_cast(bf16x8, As_[row * 8 + slot]);
        }
#pragma unroll
        for (int n = 0; n < 4; ++n) {
            int row  = wc * 64 + n * 16 + lrow;
            int slot = (ks * 4 + kgrp) ^ (row & 7);
            b[ks][n] = __builtin_bit_cast(bf16x8, Bs_[row * 8 + slot]);
        }
    }
}

__global__ void __launch_bounds__(256, 2)
graph_loss_fb(const float* __restrict__ x, const float* __restrict__ y,
              const float* __restrict__ sqx, const float* __restrict__ sqy,
              float* __restrict__ out) {
    __shared__ u16x8 As[BM * 8];
    __shared__ u16x8 Bs[BM * 8];
    __shared__ float snxA[BM], snxB[BM], snyA[BM], snyB[BM];
    __shared__ float wsum[4];

    const int tid  = threadIdx.x;
    const int lane = tid & 63;
    const int wid  = tid >> 6;
    const int wr   = wid >> 1;
    const int wc   = wid & 1;
    const int lrow = lane & 15;
    const int kgrp = lane >> 4;

    int t = blockIdx.x, bi = 0;
    while (t >= NT - bi) { t -= NT - bi; ++bi; }
    const int bj = bi + t;
    const int iA = bi * BM;
    const int iB = bj * BM;

    if (tid < BM) {
        snxA[tid] = sqx[iA + tid];
        snyA[tid] = sqy[iA + tid];
        snxB[tid] = sqx[iB + tid];
        snyB[tid] = sqy[iB + tid];
    }

    f32x4 accX[4][4] = {};
    f32x4 accY[4][4] = {};
    bf16x8 a[2][4], b[2][4];

    for (int kt = 0; kt < D_X / 64; ++kt) {
        __syncthreads();
        stage_tile_fb(x, D_X, iA, kt * 64, As, tid);
        stage_tile_fb(x, D_X, iB, kt * 64, Bs, tid);
        __syncthreads();
        load_frags_fb(As, Bs, wr, wc, lrow, kgrp, a, b);
#pragma unroll
        for (int ks = 0; ks < 2; ++ks) mfma16_fb(a[ks], b[ks], accX);
    }
    for (int kt = 0; kt < D_Y / 64; ++kt) {
        __syncthreads();
        stage_tile_fb(y, D_Y, iA, kt * 64, As, tid);
        stage_tile_fb(y, D_Y, iB, kt * 64, Bs, tid);
        __syncthreads();
        load_frags_fb(As, Bs, wr, wc, lrow, kgrp, a, b);
#pragma unroll
        for (int ks = 0; ks < 2; ++ks) mfma16_fb(a[ks], b[ks], accY);
    }

    float local = 0.f;
#pragma unroll
    for (int m = 0; m < 4; ++m) {
#pragma unroll
        for (int n = 0; n < 4; ++n) {
            int col   = wc * 64 + n * 16 + lrow;
            float sxj = snxB[col];
            float syj = snyB[col];
#pragma unroll
            for (int r = 0; r < 4; ++r) {
                int rowi  = wr * 64 + m * 16 + kgrp * 4 + r;
                float d2x = snxA[rowi] + sxj - 2.f * accX[m][n][r];
                float dxv = sqrtf(fmaxf(d2x, 1e-12f));
                float d2y = snyA[rowi] + syj - 2.f * accY[m][n][r];
                float dyv = sqrtf(fmaxf(d2y, 1e-12f));
                int gi = iA + rowi, gj = iB + col;
                bool keep = (gi != gj) && (dxv <= EPS_THR);
                float contrib = __expf(-dxv * SIGMA_INV) * dyv;
                local += keep ? contrib : 0.f;
            }
        }
    }
    if (bi != bj) local *= 2.f;

#pragma unroll
    for (int off = 32; off > 0; off >>= 1)
        local += __shfl_down(local, off, 64);
    if (lane == 0) wsum[wid] = local;
    __syncthreads();
    if (tid == 0)
        atomicAdd(out, wsum[0] + wsum[1] + wsum[2] + wsum[3]);
}

// ===========================================================================
extern "C" void kernel_launch(void* const* d_in, const int* in_sizes, int n_in,
                              void* d_out, int out_size, void* d_ws, size_t ws_size,
                              hipStream_t stream) {
    const float* x = (const float*)d_in[0];
    const float* y = (const float*)d_in[1];
    float* out = (float*)d_out;

    hipMemsetAsync(d_out, 0, sizeof(float) * (size_t)out_size, stream);

    const size_t xq_bytes = (size_t)BATCH * D_X;        // 4 MB fp8
    const size_t yq_bytes = (size_t)BATCH * D_Y;        // 2 MB fp8
    const size_t sq_bytes = 2 * (size_t)BATCH * sizeof(float);
    const size_t need = xq_bytes + yq_bytes + sq_bytes;

    if (ws_size >= need) {
        u64*   xq  = (u64*)d_ws;
        u64*   yq  = (u64*)((char*)d_ws + xq_bytes);
        float* sqx = (float*)((char*)d_ws + xq_bytes + yq_bytes);
        float* sqy = sqx + BATCH;
        convert_fp8<<<BATCH, 192, 0, stream>>>(x, y, xq, yq, sqx, sqy);
        gram_fp8<<<NBLK2, 256, 0, stream>>>((const u16x8*)xq, (const u16x8*)yq,
                                            sqx, sqy, out);
    } else {
        float* sqx = (float*)d_ws;
        float* sqy = sqx + BATCH;
        norms_kernel_fb<<<BATCH, 64, 0, stream>>>(x, y, sqx, sqy);
        graph_loss_fb<<<NBLK, 256, 0, stream>>>(x, y, sqx, sqy, out);
    }
}

// Round 14
// 57.703 us; speedup vs baseline: 1.7011x; 1.0489x over previous
//
#include <hip/hip_runtime.h>
#include <hip/hip_bf16.h>
#include <hip/hip_fp8.h>
#include <stdint.h>

// Problem constants (from reference)
#define BATCH 4096
#define D_X   1024
#define D_Y   512

constexpr float SIGMA_INV = 0.1f;    // 1/10.0
constexpr float EPS_THR   = 46.0f;

// ---- fast path: fp8 e4m3, 128x128 triangular tiles ----
constexpr int BMF   = 128;
constexpr int NTF   = BATCH / BMF;           // 32 tile-rows
constexpr int NBLKF = NTF * (NTF + 1) / 2;   // 528 (528 % 8 == 0)
constexpr int XS8   = D_X / 16;              // 64 16B slots per fp8 x row
constexpr int YS8   = D_Y / 16;              // 32 slots per fp8 y row

// ---- fallback tiling (128^2 bf16, round-2 structure) ----
constexpr int BM = 128;
constexpr int NT = BATCH / BM;
constexpr int NBLK = NT * (NT + 1) / 2;

typedef __bf16 bf16x8 __attribute__((ext_vector_type(8)));
typedef float  f32x4  __attribute__((ext_vector_type(4)));
typedef unsigned short u16x8 __attribute__((ext_vector_type(8)));
typedef unsigned long long u64;
typedef u64 u64x2 __attribute__((ext_vector_type(2)));

__device__ __forceinline__ unsigned short f32_to_bf16_bits(float f) {
    unsigned int u = __builtin_bit_cast(unsigned int, f);
    unsigned int r = (u + 0x7FFFu + ((u >> 16) & 1u)) >> 16;  // RNE
    return (unsigned short)r;
}

// k-unit permutation (R11): 16B chunk c = (ks>>1)*4 + kgrp holds ks-pair
// {2t,2t+1} of kgrp -> one conflict-free ds_read_b128 per (row, kspair).
__device__ __forceinline__ int perm16(int u8) {
    int ks = u8 >> 2, kg = u8 & 3;
    return (ks >> 1) * 8 + kg * 2 + (ks & 1);
}

// ===========================================================================
// FAST PATH kernel 1: f32 -> fp8 e4m3 (permuted k-order) + norms of the
// QUANTIZED values (so d2 = ||q_i - q_j||^2 is exact for quantized vectors).
// ===========================================================================
__global__ void __launch_bounds__(192)
convert_fp8(const float* __restrict__ x, const float* __restrict__ y,
            u64* __restrict__ xq, u64* __restrict__ yq,
            float* __restrict__ sqx, float* __restrict__ sqy) {
    __shared__ float part[2];
    const int row = blockIdx.x;
    const int t   = threadIdx.x;
    const int lane = t & 63;
    const int wid  = t >> 6;

    float nrm = 0.f;
    if (t < 128) {
        const float4* p = (const float4*)(x + (size_t)row * D_X + t * 8);
        float4 f0 = p[0], f1 = p[1];
        float e[8] = {f0.x, f0.y, f0.z, f0.w, f1.x, f1.y, f1.z, f1.w};
        u64 w = 0;
#pragma unroll
        for (int i = 0; i < 8; ++i) {
            __hip_fp8_e4m3 q(e[i]);                  // RNE + saturate (OCP)
            float b = (float)q;
            nrm = fmaf(b, b, nrm);
            w |= (u64)q.__x << (8 * i);
        }
        xq[(size_t)row * 128 + (t & ~15) + perm16(t & 15)] = w;
    } else {
        int o = t - 128;                             // 0..63
        const float4* p = (const float4*)(y + (size_t)row * D_Y + o * 8);
        float4 f0 = p[0], f1 = p[1];
        float e[8] = {f0.x, f0.y, f0.z, f0.w, f1.x, f1.y, f1.z, f1.w};
        u64 w = 0;
#pragma unroll
        for (int i = 0; i < 8; ++i) {
            __hip_fp8_e4m3 q(e[i]);
            float b = (float)q;
            nrm = fmaf(b, b, nrm);
            w |= (u64)q.__x << (8 * i);
        }
        yq[(size_t)row * 64 + (o & ~15) + perm16(o & 15)] = w;
    }
#pragma unroll
    for (int off = 32; off > 0; off >>= 1)
        nrm += __shfl_down(nrm, off, 64);
    if (lane == 0) {
        if (wid < 2) part[wid] = nrm;
        else         sqy[row] = nrm;
    }
    __syncthreads();
    if (t == 0) sqx[row] = part[0] + part[1];
}

// ===========================================================================
// FAST PATH kernel 2: 128^2 fp8 tiles. Combined A|B LDS tile [256 rows][8
// slots] = 32 KB/step, BK=128 -> 12 steps, 2 buffers (64 KB, 2 blocks/CU),
// depth-2 counted vmcnt(8). Per wave: 64x64 output, 64 MFMA/step.
// global_load_lds offset arg stays 0 (R12: the imm applies to BOTH global
// and LDS addresses); step offset is pointer arithmetic on the global side.
// ===========================================================================

__device__ __forceinline__ u64x2 ldsfrag2(const u16x8* T, int row, int c) {
    int slot = c ^ (row & 7);
    return __builtin_bit_cast(u64x2, T[row * 8 + slot]);
}

#define ISSUE(DST, BASE, OFF)                                              \
    {                                                                      \
        _Pragma("unroll")                                                  \
        for (int it = 0; it < 8; ++it)                                     \
            __builtin_amdgcn_global_load_lds(                              \
                (const uint32_t __attribute__((address_space(1)))*)(BASE[it] + (OFF)), \
                (uint32_t __attribute__((address_space(3)))*)((DST) + it * 256 + wid * 64), \
                16, 0, 0);                                                 \
    }

#define FRAGS_READ(BUF)                                                    \
        u64x2 fa[2][4], fb[2][4];   /* [kspair][frag] */                   \
        _Pragma("unroll")                                                  \
        for (int t2 = 0; t2 < 2; ++t2) {                                   \
            _Pragma("unroll")                                              \
            for (int m = 0; m < 4; ++m)                                    \
                fa[t2][m] = ldsfrag2(BUF, wr * 64 + m * 16 + lrow,         \
                                     t2 * 4 + kgrp);                       \
            _Pragma("unroll")                                              \
            for (int n = 0; n < 4; ++n)                                    \
                fb[t2][n] = ldsfrag2(BUF, 128 + wc * 64 + n * 16 + lrow,   \
                                     t2 * 4 + kgrp);                       \
        }

#define FRAGS_MFMA(ACC)                                                    \
        __builtin_amdgcn_s_setprio(1);                                     \
        _Pragma("unroll")                                                  \
        for (int t2 = 0; t2 < 2; ++t2)                                     \
            _Pragma("unroll")                                              \
            for (int h = 0; h < 2; ++h)                                    \
                _Pragma("unroll")                                          \
                for (int m = 0; m < 4; ++m)                                \
                    _Pragma("unroll")                                      \
                    for (int n = 0; n < 4; ++n)                            \
                        ACC[m][n] =                                        \
                            __builtin_amdgcn_mfma_f32_16x16x32_fp8_fp8(    \
                                (long)fa[t2][m][h], (long)fb[t2][n][h],    \
                                ACC[m][n], 0, 0, 0);                       \
        __builtin_amdgcn_s_setprio(0);

#define GSTEP(BUF, ACC, W, IBASE, IOFF)                                    \
    {                                                                      \
        asm volatile("s_waitcnt vmcnt(" #W ")" ::: "memory");              \
        __builtin_amdgcn_s_barrier();                                      \
        FRAGS_READ(BUF)                                                    \
        asm volatile("s_waitcnt lgkmcnt(0)" ::: "memory");                 \
        __builtin_amdgcn_s_barrier();                                      \
        ISSUE(BUF, IBASE, IOFF)                                            \
        FRAGS_MFMA(ACC)                                                    \
    }
#define GSTEP_NOISSUE(BUF, ACC, W)                                         \
    {                                                                      \
        asm volatile("s_waitcnt vmcnt(" #W ")" ::: "memory");              \
        __builtin_amdgcn_s_barrier();                                      \
        FRAGS_READ(BUF)                                                    \
        FRAGS_MFMA(ACC)                                                    \
    }

__global__ void __launch_bounds__(256, 2)
gram_fp8(const u16x8* __restrict__ xq, const u16x8* __restrict__ yq,
         const float* __restrict__ sqx, const float* __restrict__ sqy,
         float* __restrict__ out) {
    __shared__ u16x8 T0[2048], T1[2048];   // 2 x 32 KB combined A|B tiles
    __shared__ float snxA[BMF], snxB[BMF], snyA[BMF], snyB[BMF];
    __shared__ float wsum[4];

    const int tid  = threadIdx.x;
    const int lane = tid & 63;
    const int wid  = tid >> 6;
    const int wr   = wid >> 1;
    const int wc   = wid & 1;
    const int lrow = lane & 15;
    const int kgrp = lane >> 4;

    // XCD swizzle (bijective: NBLKF % 8 == 0).
    int sb = (blockIdx.x & 7) * (NBLKF / 8) + (blockIdx.x >> 3);

    // triangular tile mapping
    int t0 = sb, bi = 0;
    while (t0 >= NTF - bi) { t0 -= NTF - bi; ++bi; }
    const int bj = bi + t0;
    const int iA = bi * BMF;
    const int iB = bj * BMF;
    const bool diag = (bi == bj);

    if (tid < BMF) {
        snxA[tid] = sqx[iA + tid];
        snyA[tid] = sqy[iA + tid];
    } else {
        int u = tid - BMF;
        snxB[u] = sqx[iB + u];
        snyB[u] = sqy[iB + u];
    }

    // Per-lane staging base pointers: lane ul = it*256 + wid*64 + lane maps
    // to (row 0..255, stored-slot st); swizzle folded into the base.
    // X bases first; the same 8 registers are re-pointed at Y before step 6.
    const char* g[8];
#pragma unroll
    for (int it = 0; it < 8; ++it) {
        int ul   = it * 256 + wid * 64 + lane;
        int row  = ul >> 3;
        int st   = ul & 7;
        int lg   = st ^ (row & 7);
        int grow = (row < 128 ? iA + row : iB + row - 128);
        g[it] = (const char*)xq + (size_t)grow * (XS8 * 16) + lg * 16;
    }

    f32x4 accX[4][4] = {};
    f32x4 accY[4][4] = {};

    // prologue: pre-issue steps 0,1 (16 loads in flight; no drain)
    ISSUE(T0, g, 0)
    ISSUE(T1, g, 128)

    // X phase: steps 0..5 stage from xq (offsets s*128)
    GSTEP(T0, accX, 8, g, 256)   // s=0, issues s=2
    GSTEP(T1, accX, 8, g, 384)   // s=1, issues s=3
    GSTEP(T0, accX, 8, g, 512)   // s=2, issues s=4
    GSTEP(T1, accX, 8, g, 640)   // s=3, issues s=5
    GSTEP(T0, accX, 8, g, 768)   // s=4, issues s=6
    GSTEP(T1, accX, 8, g, 896)   // s=5, issues s=7

    // switch bases to yq (same registers; per-thread, no sync needed)
#pragma unroll
    for (int it = 0; it < 8; ++it) {
        int ul   = it * 256 + wid * 64 + lane;
        int row  = ul >> 3;
        int st   = ul & 7;
        int lg   = st ^ (row & 7);
        int grow = (row < 128 ? iA + row : iB + row - 128);
        g[it] = (const char*)yq + (size_t)grow * (YS8 * 16) + lg * 16;
    }

    GSTEP(T0, accX, 8, g, 0)     // s=6, issues s=8  (first Y step)
    GSTEP(T1, accX, 8, g, 128)   // s=7, issues s=9
    GSTEP(T0, accY, 8, g, 256)   // s=8, issues s=10
    GSTEP(T1, accY, 8, g, 384)   // s=9, issues s=11
    GSTEP_NOISSUE(T0, accY, 8)   // s=10 (batch 11 in flight)
    GSTEP_NOISSUE(T1, accY, 0)   // s=11 (full drain)

    // Epilogue: C/D layout col=lane&15, row=(lane>>4)*4+reg (m89, dtype-indep)
    float local = 0.f;
#pragma unroll
    for (int m = 0; m < 4; ++m) {
#pragma unroll
        for (int n = 0; n < 4; ++n) {
            int col   = wc * 64 + n * 16 + lrow;
            float sxj = snxB[col];
            float syj = snyB[col];
#pragma unroll
            for (int r = 0; r < 4; ++r) {
                int rowi  = wr * 64 + m * 16 + kgrp * 4 + r;
                float d2x = snxA[rowi] + sxj - 2.f * accX[m][n][r];
                float dxv = sqrtf(fmaxf(d2x, 1e-12f));
                float d2y = snyA[rowi] + syj - 2.f * accY[m][n][r];
                float dyv = sqrtf(fmaxf(d2y, 1e-12f));
                int gi = iA + rowi, gj = iB + col;
                bool keep = (gi != gj) && (dxv <= EPS_THR);
                float contrib = __expf(-dxv * SIGMA_INV) * dyv;
                local += keep ? contrib : 0.f;
            }
        }
    }
    if (!diag) local *= 2.f;

#pragma unroll
    for (int off = 32; off > 0; off >>= 1)
        local += __shfl_down(local, off, 64);
    if (lane == 0) wsum[wid] = local;
    __syncthreads();
    if (tid == 0)
        atomicAdd(out, wsum[0] + wsum[1] + wsum[2] + wsum[3]);
}

// ===========================================================================
// FALLBACK PATH (bf16, round-2 structure) — used only if ws too small.
// ===========================================================================
__global__ void norms_kernel_fb(const float* __restrict__ x,
                                const float* __restrict__ y,
                                float* __restrict__ sqx,
                                float* __restrict__ sqy) {
    int row = blockIdx.x;
    int t   = threadIdx.x;
    const float4* xr = (const float4*)(x + (size_t)row * D_X);
    float sx = 0.f;
#pragma unroll
    for (int i = 0; i < D_X / 4 / 64; ++i) {
        float4 v = xr[t + i * 64];
        sx += v.x * v.x + v.y * v.y + v.z * v.z + v.w * v.w;
    }
    const float4* yr = (const float4*)(y + (size_t)row * D_Y);
    float sy = 0.f;
#pragma unroll
    for (int i = 0; i < D_Y / 4 / 64; ++i) {
        float4 v = yr[t + i * 64];
        sy += v.x * v.x + v.y * v.y + v.z * v.z + v.w * v.w;
    }
#pragma unroll
    for (int off = 32; off > 0; off >>= 1) {
        sx += __shfl_down(sx, off, 64);
        sy += __shfl_down(sy, off, 64);
    }
    if (t == 0) { sqx[row] = sx; sqy[row] = sy; }
}

__device__ __forceinline__ void stage_tile_fb(const float* __restrict__ src, int ld,
                                              int base_row, int k0,
                                              u16x8* __restrict__ dst, int tid) {
#pragma unroll
    for (int it = 0; it < 2; ++it) {
        int u   = tid + it * 256;
        int row = u >> 2;
        int q   = u & 3;
        const float4* p = (const float4*)(src + (size_t)(base_row + row) * ld + k0 + q * 16);
        float4 f0 = p[0], f1 = p[1], f2 = p[2], f3 = p[3];
        u16x8 lo, hi;
        lo[0] = f32_to_bf16_bits(f0.x); lo[1] = f32_to_bf16_bits(f0.y);
        lo[2] = f32_to_bf16_bits(f0.z); lo[3] = f32_to_bf16_bits(f0.w);
        lo[4] = f32_to_bf16_bits(f1.x); lo[5] = f32_to_bf16_bits(f1.y);
        lo[6] = f32_to_bf16_bits(f1.z); lo[7] = f32_to_bf16_bits(f1.w);
        hi[0] = f32_to_bf16_bits(f2.x); hi[1] = f32_to_bf16_bits(f2.y);
        hi[2] = f32_to_bf16_bits(f2.z); hi[3] = f32_to_bf16_bits(f2.w);
        hi[4] = f32_to_bf16_bits(f3.x); hi[5] = f32_to_bf16_bits(f3.y);
        hi[6] = f32_to_bf16_bits(f3.z); hi[7] = f32_to_bf16_bits(f3.w);
        int swz = row & 7;
        dst[row * 8 + ((2 * q) ^ swz)]     = lo;
        dst[row * 8 + ((2 * q + 1) ^ swz)] = hi;
    }
}

__device__ __forceinline__ void mfma16_fb(const bf16x8 a[4], const bf16x8 b[4],
                                          f32x4 acc[4][4]) {
#pragma unroll
    for (int m = 0; m < 4; ++m)
#pragma unroll
        for (int n = 0; n < 4; ++n)
            acc[m][n] = __builtin_amdgcn_mfma_f32_16x16x32_bf16(
                a[m], b[n], acc[m][n], 0, 0, 0);
}

__device__ __forceinline__ void load_frags_fb(const u16x8* As_, const u16x8* Bs_,
                                              int wr, int wc, int lrow, int kgrp,
                                              bf16x8 a[2][4], bf16x8 b[2][4]) {
#pragma unroll
    for (int ks = 0; ks < 2; ++ks) {
#pragma unroll
        for (int m = 0; m < 4; ++m) {
            int row  = wr * 64 + m * 16 + lrow;
            int slot = (ks * 4 + kgrp) ^ (row & 7);
            a[ks][m] = __builtin_bit_cast(bf16x8, As_[row * 8 + slot]);
        }
#pragma unroll
        for (int n = 0; n < 4; ++n) {
            int row  = wc * 64 + n * 16 + lrow;
            int slot = (ks * 4 + kgrp) ^ (row & 7);
            b[ks][n] = __builtin_bit_cast(bf16x8, Bs_[row * 8 + slot]);
        }
    }
}

__global__ void __launch_bounds__(256, 2)
graph_loss_fb(const float* __restrict__ x, const float* __restrict__ y,
              const float* __restrict__ sqx, const float* __restrict__ sqy,
              float* __restrict__ out) {
    __shared__ u16x8 As[BM * 8];
    __shared__ u16x8 Bs[BM * 8];
    __shared__ float snxA[BM], snxB[BM], snyA[BM], snyB[BM];
    __shared__ float wsum[4];

    const int tid  = threadIdx.x;
    const int lane = tid & 63;
    const int wid  = tid >> 6;
    const int wr   = wid >> 1;
    const int wc   = wid & 1;
    const int lrow = lane & 15;
    const int kgrp = lane >> 4;

    int t = blockIdx.x, bi = 0;
    while (t >= NT - bi) { t -= NT - bi; ++bi; }
    const int bj = bi + t;
    const int iA = bi * BM;
    const int iB = bj * BM;

    if (tid < BM) {
        snxA[tid] = sqx[iA + tid];
        snyA[tid] = sqy[iA + tid];
        snxB[tid] = sqx[iB + tid];
        snyB[tid] = sqy[iB + tid];
    }

    f32x4 accX[4][4] = {};
    f32x4 accY[4][4] = {};
    bf16x8 a[2][4], b[2][4];

    for (int kt = 0; kt < D_X / 64; ++kt) {
        __syncthreads();
        stage_tile_fb(x, D_X, iA, kt * 64, As, tid);
        stage_tile_fb(x, D_X, iB, kt * 64, Bs, tid);
        __syncthreads();
        load_frags_fb(As, Bs, wr, wc, lrow, kgrp, a, b);
#pragma unroll
        for (int ks = 0; ks < 2; ++ks) mfma16_fb(a[ks], b[ks], accX);
    }
    for (int kt = 0; kt < D_Y / 64; ++kt) {
        __syncthreads();
        stage_tile_fb(y, D_Y, iA, kt * 64, As, tid);
        stage_tile_fb(y, D_Y, iB, kt * 64, Bs, tid);
        __syncthreads();
        load_frags_fb(As, Bs, wr, wc, lrow, kgrp, a, b);
#pragma unroll
        for (int ks = 0; ks < 2; ++ks) mfma16_fb(a[ks], b[ks], accY);
    }

    float local = 0.f;
#pragma unroll
    for (int m = 0; m < 4; ++m) {
#pragma unroll
        for (int n = 0; n < 4; ++n) {
            int col   = wc * 64 + n * 16 + lrow;
            float sxj = snxB[col];
            float syj = snyB[col];
#pragma unroll
            for (int r = 0; r < 4; ++r) {
                int rowi  = wr * 64 + m * 16 + kgrp * 4 + r;
                float d2x = snxA[rowi] + sxj - 2.f * accX[m][n][r];
                float dxv = sqrtf(fmaxf(d2x, 1e-12f));
                float d2y = snyA[rowi] + syj - 2.f * accY[m][n][r];
                float dyv = sqrtf(fmaxf(d2y, 1e-12f));
                int gi = iA + rowi, gj = iB + col;
                bool keep = (gi != gj) && (dxv <= EPS_THR);
                float contrib = __expf(-dxv * SIGMA_INV) * dyv;
                local += keep ? contrib : 0.f;
            }
        }
    }
    if (bi != bj) local *= 2.f;

#pragma unroll
    for (int off = 32; off > 0; off >>= 1)
        local += __shfl_down(local, off, 64);
    if (lane == 0) wsum[wid] = local;
    __syncthreads();
    if (tid == 0)
        atomicAdd(out, wsum[0] + wsum[1] + wsum[2] + wsum[3]);
}

// ===========================================================================
extern "C" void kernel_launch(void* const* d_in, const int* in_sizes, int n_in,
                              void* d_out, int out_size, void* d_ws, size_t ws_size,
                              hipStream_t stream) {
    const float* x = (const float*)d_in[0];
    const float* y = (const float*)d_in[1];
    float* out = (float*)d_out;

    hipMemsetAsync(d_out, 0, sizeof(float) * (size_t)out_size, stream);

    const size_t xq_bytes = (size_t)BATCH * D_X;        // 4 MB fp8
    const size_t yq_bytes = (size_t)BATCH * D_Y;        // 2 MB fp8
    const size_t sq_bytes = 2 * (size_t)BATCH * sizeof(float);
    const size_t need = xq_bytes + yq_bytes + sq_bytes;

    if (ws_size >= need) {
        u64*   xq  = (u64*)d_ws;
        u64*   yq  = (u64*)((char*)d_ws + xq_bytes);
        float* sqx = (float*)((char*)d_ws + xq_bytes + yq_bytes);
        float* sqy = sqx + BATCH;
        convert_fp8<<<BATCH, 192, 0, stream>>>(x, y, xq, yq, sqx, sqy);
        gram_fp8<<<NBLKF, 256, 0, stream>>>((const u16x8*)xq, (const u16x8*)yq,
                                            sqx, sqy, out);
    } else {
        float* sqx = (float*)d_ws;
        float* sqy = sqx + BATCH;
        norms_kernel_fb<<<BATCH, 64, 0, stream>>>(x, y, sqx, sqy);
        graph_loss_fb<<<NBLK, 256, 0, stream>>>(x, y, sqx, sqy, out);
    }
}